// Round 22
// baseline (154.886 us; speedup 1.0000x reference)
//
#include <hip/hip_runtime.h>
#include <hip/hip_bf16.h>

#define T_TOKENS 2048
#define HID 1024
#define ISZ 1408
#define NEXP 8
#define TILES_MAX 72    // sum ceil(cnt_e/64) <= 4096/64 + 8 = 72

typedef __bf16 bf16x8 __attribute__((ext_vector_type(8)));
typedef __bf16 bf16x4 __attribute__((ext_vector_type(4)));
typedef float  f32x16 __attribute__((ext_vector_type(16)));

__device__ __forceinline__ void gload16(const void* g, void* l) {
    __builtin_amdgcn_global_load_lds(
        (const __attribute__((address_space(1))) void*)g,
        (__attribute__((address_space(3))) void*)l,
        16, 0, 0);
}

// counted-vmcnt barrier: newest N loads may stay in flight; everything older done.
#define PIPE_BARRIER(N)                                              \
    asm volatile("s_waitcnt vmcnt(" #N ") lgkmcnt(0)" ::: "memory"); \
    __builtin_amdgcn_sched_barrier(0);                               \
    __builtin_amdgcn_s_barrier();                                    \
    __builtin_amdgcn_sched_barrier(0);

// ---------------- tcvt: 128(in-rows) x 64(in-cols) tile per block ----------------
// Output rows are 256B contiguous (write-granularity experiment). [128][65] LDS, 16.6 KB.
__global__ __launch_bounds__(256) void tcvt_all_kernel(
    const float* __restrict__ wg, const float* __restrict__ wu, const float* __restrict__ wd,
    __bf16* __restrict__ wgT, __bf16* __restrict__ wuT, __bf16* __restrict__ wdT)
{
    const int z  = blockIdx.y;         // 0..23
    const int bx = blockIdx.x;         // 0..175
    const int e  = z & 7;
    const float* in;
    __bf16* out;
    int R, C, rr, cc;
    if (z < 16) {
        R = HID; C = ISZ;              // in [1024][1408]
        rr = (bx / 22) * 128;          // 8 row-groups
        cc = (bx % 22) * 64;           // 22 col-groups
        in  = (z < 8 ? wg : wu)  + (size_t)e * R * C;
        out = (z < 8 ? wgT : wuT) + (size_t)e * R * C;
    } else {
        R = ISZ; C = HID;              // in [1408][1024]
        rr = (bx / 16) * 128;          // 11 row-groups
        cc = (bx % 16) * 64;           // 16 col-groups
        in  = wd  + (size_t)e * R * C;
        out = wdT + (size_t)e * R * C;
    }
    __shared__ __bf16 tb[128][65];     // 16.6 KB
    const int tid  = threadIdx.x;
    const int lrow = tid >> 4;         // 0..15
    const int lc4  = (tid & 15) * 4;

    #pragma unroll
    for (int p = 0; p < 8; ++p) {
        float4 v = *(const float4*)(in + (size_t)(rr + p * 16 + lrow) * C + cc + lc4);
        bf16x4 w;
        w[0] = (__bf16)v.x; w[1] = (__bf16)v.y; w[2] = (__bf16)v.z; w[3] = (__bf16)v.w;
        *(bf16x4*)&tb[p * 16 + lrow][lc4] = w;
    }
    __syncthreads();
    // transposed store: out row oc (= in col, 64 rows), 256B contiguous per row
    #pragma unroll
    for (int q = 0; q < 4; ++q) {
        const int idx = q * 256 + tid;
        const int oc  = idx >> 4;          // 0..63
        const int vs  = (idx & 15) * 8;    // 0..120
        bf16x8 w;
        #pragma unroll
        for (int j = 0; j < 8; ++j) w[j] = tb[vs + j][oc];
        *(bf16x8*)(out + (size_t)(cc + oc) * R + rr + vs) = w;
    }
}

// ---------------- Router: 512 blocks x 4 waves, one token/wave, ZERO LDS (R19-verified) --
__global__ __launch_bounds__(256) void router_kernel(
    const float* __restrict__ x, const float* __restrict__ gw,
    int* __restrict__ sel, float* __restrict__ wt, __bf16* __restrict__ xb)
{
    const int tid  = threadIdx.x;
    const int wave = tid >> 6;
    const int lane = tid & 63;
    const int t = blockIdx.x * 4 + wave;
    const float* xr = x + (size_t)t * HID;

    const int c0 = lane * 16;
    float4 v0 = *(const float4*)(xr + c0);
    float4 v1 = *(const float4*)(xr + c0 + 4);
    float4 v2 = *(const float4*)(xr + c0 + 8);
    float4 v3 = *(const float4*)(xr + c0 + 12);
    {
        bf16x8 o0, o1;
        o0[0]=(__bf16)v0.x; o0[1]=(__bf16)v0.y; o0[2]=(__bf16)v0.z; o0[3]=(__bf16)v0.w;
        o0[4]=(__bf16)v1.x; o0[5]=(__bf16)v1.y; o0[6]=(__bf16)v1.z; o0[7]=(__bf16)v1.w;
        o1[0]=(__bf16)v2.x; o1[1]=(__bf16)v2.y; o1[2]=(__bf16)v2.z; o1[3]=(__bf16)v2.w;
        o1[4]=(__bf16)v3.x; o1[5]=(__bf16)v3.y; o1[6]=(__bf16)v3.z; o1[7]=(__bf16)v3.w;
        *(bf16x8*)(xb + (size_t)t * HID + c0) = o0;
        *(bf16x8*)(xb + (size_t)t * HID + c0 + 8) = o1;
    }
    if (blockIdx.x == 0 && tid < 128) {   // zero pad-row
        bf16x8 z8;
        #pragma unroll
        for (int j = 0; j < 8; ++j) z8[j] = (__bf16)0.f;
        *(bf16x8*)(xb + (size_t)T_TOKENS * HID + tid * 8) = z8;
    }

    float le[8] = {0.f, 0.f, 0.f, 0.f, 0.f, 0.f, 0.f, 0.f};
    float xv[16];
    xv[0]=v0.x; xv[1]=v0.y; xv[2]=v0.z; xv[3]=v0.w;
    xv[4]=v1.x; xv[5]=v1.y; xv[6]=v1.z; xv[7]=v1.w;
    xv[8]=v2.x; xv[9]=v2.y; xv[10]=v2.z; xv[11]=v2.w;
    xv[12]=v3.x; xv[13]=v3.y; xv[14]=v3.z; xv[15]=v3.w;
    #pragma unroll
    for (int j = 0; j < 16; ++j) {
        const float* gr = gw + (size_t)(c0 + j) * NEXP;
        float4 g0 = *(const float4*)gr;
        float4 g1 = *(const float4*)(gr + 4);
        le[0] += xv[j] * g0.x; le[1] += xv[j] * g0.y;
        le[2] += xv[j] * g0.z; le[3] += xv[j] * g0.w;
        le[4] += xv[j] * g1.x; le[5] += xv[j] * g1.y;
        le[6] += xv[j] * g1.z; le[7] += xv[j] * g1.w;
    }
    #pragma unroll
    for (int d = 1; d < 64; d <<= 1) {
        #pragma unroll
        for (int k = 0; k < 8; ++k) le[k] += __shfl_xor(le[k], d);
    }
    float m = le[0];
    #pragma unroll
    for (int k = 1; k < 8; ++k) m = fmaxf(m, le[k]);
    float pe[8]; float s = 0.f;
    #pragma unroll
    for (int k = 0; k < 8; ++k) { pe[k] = expf(le[k] - m); s += pe[k]; }
    int e1 = 0; float p1 = pe[0];
    #pragma unroll
    for (int k = 1; k < 8; ++k) if (pe[k] > p1) { p1 = pe[k]; e1 = k; }
    int e2 = -1; float p2 = -1.f;
    #pragma unroll
    for (int k = 0; k < 8; ++k) if (k != e1 && pe[k] > p2) { p2 = pe[k]; e2 = k; }
    if (lane == 0) {
        float inv = 1.0f / (p1 + p2);
        sel[t * 2 + 0] = e1; sel[t * 2 + 1] = e2;
        wt[t * 2 + 0] = p1 * inv; wt[t * 2 + 1] = p2 * inv;
    }
}

// ---------------- Histogram + scan + assign + tile table (single block) ----------------
__global__ __launch_bounds__(256) void scan_assign_kernel(
    int* __restrict__ tiles,
    const int* __restrict__ sel, const float* __restrict__ wt,
    int* __restrict__ rtok, float* __restrict__ rwt, int* __restrict__ tok2row)
{
    __shared__ int hist[NEXP];
    __shared__ int soff[NEXP];
    __shared__ int scur[NEXP];
    if (threadIdx.x < NEXP) { hist[threadIdx.x] = 0; scur[threadIdx.x] = 0; }
    __syncthreads();
    for (int t = threadIdx.x; t < T_TOKENS; t += 256) {
        atomicAdd(&hist[sel[t * 2 + 0]], 1);
        atomicAdd(&hist[sel[t * 2 + 1]], 1);
    }
    __syncthreads();
    if (threadIdx.x == 0) {
        int cur = 0, tix = 0;
        for (int e = 0; e < NEXP; ++e) {
            soff[e] = cur;
            int n64 = (hist[e] + 63) & ~63;            // 64-row tile alignment
            for (int rt = 0; rt * 64 < n64; ++rt)
                tiles[tix++] = (e << 16) | (cur + rt * 64);
            cur += n64;
        }
        for (; tix < TILES_MAX; ++tix) tiles[tix] = -1;
    }
    __syncthreads();
    for (int t = threadIdx.x; t < T_TOKENS; t += 256) {
        #pragma unroll
        for (int k = 0; k < 2; ++k) {
            int e = sel[t * 2 + k];
            int pos = atomicAdd(&scur[e], 1);
            int row = soff[e] + pos;
            rtok[row] = t + 1;          // sentinel: 0 = pad row
            rwt[row] = wt[t * 2 + k];
            tok2row[t * 2 + k] = row;
        }
    }
}

// ---------------- FFN1: inter = silu(x@WgT') * (x@WuT') ----------------
// BM=64, BN=64(G)+64(U), BK=32, 32x32x16 MFMA, 4 waves 2x2 (each 32r x 32c of G AND U).
// 4-buf depth-3 counted-vmcnt pipeline (3 loads/stage, vmcnt(6)). 48 KB -> 3 blocks/CU.
__global__ __launch_bounds__(256) void ffn1_kernel(
    const __bf16* __restrict__ xb, const int* __restrict__ rtok,
    const __bf16* __restrict__ wgT, const __bf16* __restrict__ wuT,
    const int* __restrict__ tiles, __bf16* __restrict__ inter)
{
    // grid 1584 = 22 stripes x 72 tiles; XCD chunks of 198
    const int n  = blockIdx.x;
    const int nn = (n & 7) * 198 + (n >> 3);
    const int i0 = (nn / TILES_MAX) * 64;      // stripe 0..21
    const int tv = tiles[nn % TILES_MAX];
    if (tv < 0) return;
    const int e = tv >> 16;
    const int rowbase = tv & 0xFFFF;

    __shared__ __align__(16) __bf16 sA[4][64][32];  // 16 KB
    __shared__ __align__(16) __bf16 sG[4][64][32];  // 16 KB
    __shared__ __align__(16) __bf16 sU[4][64][32];  // 16 KB -> 48 KB

    const int lane = threadIdx.x & 63;
    const int wid  = threadIdx.x >> 6;
    const int wr = wid >> 1, wc = wid & 1;
    const int l31 = lane & 31;
    const int kg  = lane >> 5;                 // k-half 0/1

    // staging: gload16 covers 16 rows x 64B; lane: row = lane>>2, slot = lane&3.
    // slot s at row R holds global chunk s ^ ((R>>1)&3)  (involution).
    const int r16 = lane >> 2;
    const int cz  = (((lane & 3) ^ ((r16 >> 1) & 3)) * 8);
    const int rowA = rowbase + wid * 16 + r16;
    const int tokp = rtok[rowA];
    const int src  = tokp ? (tokp - 1) : T_TOKENS;     // pad rows -> zero row
    const __bf16* A0 = xb + (size_t)src * HID + cz;
    const size_t wb = (size_t)e * ISZ * HID + (size_t)(i0 + wid * 16 + r16) * HID + cz;
    const __bf16* G0 = wgT + wb;
    const __bf16* U0 = wuT + wb;

    f32x16 accG, accU;
    #pragma unroll
    for (int r = 0; r < 16; ++r) { accG[r] = 0.f; accU[r] = 0.f; }

    auto stage = [&](int b, int k0) {   // 3 gload16 per wave
        gload16(A0 + k0, &sA[b][wid * 16][0]);
        gload16(G0 + k0, &sG[b][wid * 16][0]);
        gload16(U0 + k0, &sU[b][wid * 16][0]);
    };
    auto compute = [&](int b) {
        #pragma unroll
        for (int s = 0; s < 2; ++s) {
            const int ch = ((2 * s + kg) ^ ((l31 >> 1) & 3)) * 8;
            bf16x8 a_ = *(const bf16x8*)&sA[b][wr * 32 + l31][ch];
            bf16x8 g_ = *(const bf16x8*)&sG[b][wc * 32 + l31][ch];
            bf16x8 u_ = *(const bf16x8*)&sU[b][wc * 32 + l31][ch];
            __builtin_amdgcn_s_setprio(1);
            accG = __builtin_amdgcn_mfma_f32_32x32x16_bf16(a_, g_, accG, 0, 0, 0);
            accU = __builtin_amdgcn_mfma_f32_32x32x16_bf16(a_, u_, accU, 0, 0, 0);
            __builtin_amdgcn_s_setprio(0);
        }
    };

    const int nIter = HID / 32;   // 32
    stage(0, 0);
    stage(1, 32);
    stage(2, 64);
    PIPE_BARRIER(6)               // stage0 landed; stages 1,2 (6 loads) in flight
    for (int i = 0; i < nIter; ++i) {
        int ks = (i + 3 < nIter) ? (i + 3) * 32 : 0;   // clamped dead stage keeps counts uniform
        stage((i + 3) & 3, ks);
        compute(i & 3);
        PIPE_BARRIER(6)           // stage(i+1) landed; newest 2 stages in flight
    }

    // epilogue: silu(G)*U -> bf16 inter (D: col = lane&31, row = (r&3)+8*(r>>2)+4*kg)
    const int base_row = rowbase + wr * 32;
    #pragma unroll
    for (int r = 0; r < 16; ++r) {
        float g = accG[r];
        float u = accU[r];
        float v = g / (1.0f + __expf(-g)) * u;
        int row = base_row + (r & 3) + 8 * (r >> 2) + 4 * kg;
        inter[(size_t)row * ISZ + i0 + wc * 32 + l31] = (__bf16)v;
    }
}

// ---------------- FFN2: y[row] = rwt[row] * (inter[row] @ WdT')  (no atomics) ----------------
// BM=64, BN=128, BK=32, 4 waves 2x2: wave = 32 rows x 64 cols (two 32-col MFMA tiles).
// 4-buf depth-3 counted-vmcnt (3 loads/stage, vmcnt(6)). 48 KB -> 3 blocks/CU.
__global__ __launch_bounds__(256) void ffn2_kernel(
    const __bf16* __restrict__ inter, const __bf16* __restrict__ wdT,
    const float* __restrict__ rwt, const int* __restrict__ tiles,
    float* __restrict__ y)
{
    // grid 576 = 8 stripes x 72 tiles; XCD chunks of 72
    const int n  = blockIdx.x;
    const int nn = (n & 7) * 72 + (n >> 3);
    const int n0 = (nn / TILES_MAX) * 128;     // stripe 0..7
    const int tv = tiles[nn % TILES_MAX];
    if (tv < 0) return;
    const int e = tv >> 16;
    const int rowbase = tv & 0xFFFF;

    __shared__ __align__(16) __bf16 sA[4][64][32];   // 16 KB
    __shared__ __align__(16) __bf16 sB[4][128][32];  // 32 KB -> 48 KB

    const int lane = threadIdx.x & 63;
    const int wid  = threadIdx.x >> 6;
    const int wr = wid >> 1, wc = wid & 1;
    const int l31 = lane & 31;
    const int kg  = lane >> 5;

    const int r16 = lane >> 2;
    const int cz  = (((lane & 3) ^ ((r16 >> 1) & 3)) * 8);
    const __bf16* A0 = inter + (size_t)(rowbase + wid * 16 + r16) * ISZ + cz;
    const __bf16* B0 = wdT + (size_t)e * HID * ISZ + (size_t)(n0 + wid * 32 + r16) * ISZ + cz;
    const size_t rstepB = (size_t)16 * ISZ;

    f32x16 acc[2];
    #pragma unroll
    for (int q = 0; q < 2; ++q)
        #pragma unroll
        for (int r = 0; r < 16; ++r) acc[q][r] = 0.f;

    auto stage = [&](int b, int k0) {   // 3 gload16 per wave
        gload16(A0 + k0,          &sA[b][wid * 16][0]);
        gload16(B0 + k0,          &sB[b][wid * 32][0]);
        gload16(B0 + k0 + rstepB, &sB[b][wid * 32 + 16][0]);
    };
    auto compute = [&](int b) {
        #pragma unroll
        for (int s = 0; s < 2; ++s) {
            const int ch = ((2 * s + kg) ^ ((l31 >> 1) & 3)) * 8;
            bf16x8 a_ = *(const bf16x8*)&sA[b][wr * 32 + l31][ch];
            bf16x8 b0 = *(const bf16x8*)&sB[b][wc * 64 + l31][ch];
            bf16x8 b1 = *(const bf16x8*)&sB[b][wc * 64 + 32 + l31][ch];
            __builtin_amdgcn_s_setprio(1);
            acc[0] = __builtin_amdgcn_mfma_f32_32x32x16_bf16(a_, b0, acc[0], 0, 0, 0);
            acc[1] = __builtin_amdgcn_mfma_f32_32x32x16_bf16(a_, b1, acc[1], 0, 0, 0);
            __builtin_amdgcn_s_setprio(0);
        }
    };

    const int nIter = ISZ / 32;   // 44
    stage(0, 0);
    stage(1, 32);
    stage(2, 64);
    PIPE_BARRIER(6)
    for (int i = 0; i < nIter; ++i) {
        int ks = (i + 3 < nIter) ? (i + 3) * 32 : 0;
        stage((i + 3) & 3, ks);
        compute(i & 3);
        PIPE_BARRIER(6)
    }

    const int base_row = rowbase + wr * 32;
    #pragma unroll
    for (int q = 0; q < 2; ++q) {
        const int col = n0 + wc * 64 + q * 32 + l31;
        #pragma unroll
        for (int r = 0; r < 16; ++r) {
            int row = base_row + (r & 3) + 8 * (r >> 2) + 4 * kg;
            y[(size_t)row * HID + col] = rwt[row] * acc[q][r];
        }
    }
}

// ---------------- Combine: out[t] = y[row0(t)] + y[row1(t)] ----------------
__global__ __launch_bounds__(256) void combine_kernel(
    const float* __restrict__ y, const int* __restrict__ tok2row, float* __restrict__ out)
{
    const int idx = blockIdx.x * 256 + threadIdx.x;
    const int t = idx >> 8;
    const int c = (idx & 255) * 4;
    const int r0 = tok2row[t * 2];
    const int r1 = tok2row[t * 2 + 1];
    float4 a = *(const float4*)(y + (size_t)r0 * HID + c);
    float4 b = *(const float4*)(y + (size_t)r1 * HID + c);
    float4 o = {a.x + b.x, a.y + b.y, a.z + b.z, a.w + b.w};
    *(float4*)(out + (size_t)t * HID + c) = o;
}

extern "C" void kernel_launch(void* const* d_in, const int* in_sizes, int n_in,
                              void* d_out, int out_size, void* d_ws, size_t ws_size,
                              hipStream_t stream) {
    const float* x  = (const float*)d_in[0];
    const float* gw = (const float*)d_in[1];
    const float* wg = (const float*)d_in[2];
    const float* wu = (const float*)d_in[3];
    const float* wd = (const float*)d_in[4];
    float* out = (float*)d_out;

    char* ws = (char*)d_ws;
    int*    tiles   = (int*)(ws + 64);           // 72 ints
    int*    sel     = (int*)(ws + 1024);         // 4096 ints
    float*  wtp     = (float*)(ws + 17408);      // 4096 f32
    int*    rtok    = (int*)(ws + 33792);        // 4608 ints
    float*  rwt     = (float*)(ws + 52224);      // 4608 f32
    int*    tok2row = (int*)(ws + 70656);        // 4096 ints -> ends 87040
    __bf16* xb      = (__bf16*)(ws + 87040);     // 2049*1024 bf16 = 4.20 MB
    __bf16* inter   = (__bf16*)(ws + 4283648);   // 4608*1408 bf16 = 12.98 MB
    __bf16* wgT     = (__bf16*)(ws + 17260032);  // 23.07 MB
    __bf16* wuT     = (__bf16*)(ws + 40328704);  // 23.07 MB
    __bf16* wdT     = (__bf16*)(ws + 63397376);  // 23.07 MB -> ends 86.5 MB
    float*  y       = (float*)wgT;               // alias: wgT dead after ffn1 (18.9 <= 23.07 MB)

    // zero: tiles + rtok (sentinel 0 = pad) + rwt + headers
    hipMemsetAsync(ws, 0, 87040, stream);

    tcvt_all_kernel<<<dim3(176, 24), 256, 0, stream>>>(wg, wu, wd, wgT, wuT, wdT);
    router_kernel<<<T_TOKENS / 4, 256, 0, stream>>>(x, gw, sel, wtp, xb);
    scan_assign_kernel<<<1, 256, 0, stream>>>(tiles, sel, wtp, rtok, rwt, tok2row);

    ffn1_kernel<<<22 * TILES_MAX, 256, 0, stream>>>(xb, rtok, wgT, wuT, tiles, inter);  // 1584
    ffn2_kernel<<<8 * TILES_MAX, 256, 0, stream>>>(inter, wdT, rwt, tiles, y);          // 576
    combine_kernel<<<(T_TOKENS * HID / 4) / 256, 256, 0, stream>>>(y, tok2row, out);
}

// Round 23
// 144.470 us; speedup vs baseline: 1.0721x; 1.0721x over previous
//
#include <hip/hip_runtime.h>
#include <hip/hip_bf16.h>

#define T_TOKENS 2048
#define HID 1024
#define ISZ 1408
#define NEXP 8
#define TILES_MAX 72    // sum ceil(cnt_e/64) <= 4096/64 + 8 = 72

typedef __bf16 bf16x8 __attribute__((ext_vector_type(8)));
typedef __bf16 bf16x4 __attribute__((ext_vector_type(4)));
typedef float  f32x16 __attribute__((ext_vector_type(16)));

__device__ __forceinline__ void gload16(const void* g, void* l) {
    __builtin_amdgcn_global_load_lds(
        (const __attribute__((address_space(1))) void*)g,
        (__attribute__((address_space(3))) void*)l,
        16, 0, 0);
}

// counted-vmcnt barrier: newest N loads may stay in flight; everything older done.
#define PIPE_BARRIER(N)                                              \
    asm volatile("s_waitcnt vmcnt(" #N ") lgkmcnt(0)" ::: "memory"); \
    __builtin_amdgcn_sched_barrier(0);                               \
    __builtin_amdgcn_s_barrier();                                    \
    __builtin_amdgcn_sched_barrier(0);

// ---------------- prep: router role (blocks 0..511, HEAD) + tcvt role (512..4735) --------
// router: ZERO LDS, one token/wave (R19-verified math). Runs first, hides under tcvt.
// tcvt: 2x 64x64 tiles per block, bf16-LDS pipeline (R16/R21-measured).
__global__ __launch_bounds__(256) void prep_kernel(
    const float* __restrict__ x, const float* __restrict__ gw,
    int* __restrict__ sel, float* __restrict__ wt, __bf16* __restrict__ xb,
    const float* __restrict__ wg, const float* __restrict__ wu, const float* __restrict__ wd,
    __bf16* __restrict__ wgT, __bf16* __restrict__ wuT, __bf16* __restrict__ wdT)
{
    __shared__ __bf16 tb[2][64][70];   // 17.9 KB (tcvt role; router blocks leave it unused)
    const int bid = blockIdx.x;
    const int tid = threadIdx.x;

    if (bid < 512) {
        // ---- router role ----
        const int wave = tid >> 6;
        const int lane = tid & 63;
        const int t = bid * 4 + wave;
        const float* xr = x + (size_t)t * HID;

        const int c0 = lane * 16;
        float4 v0 = *(const float4*)(xr + c0);
        float4 v1 = *(const float4*)(xr + c0 + 4);
        float4 v2 = *(const float4*)(xr + c0 + 8);
        float4 v3 = *(const float4*)(xr + c0 + 12);
        {
            bf16x8 o0, o1;
            o0[0]=(__bf16)v0.x; o0[1]=(__bf16)v0.y; o0[2]=(__bf16)v0.z; o0[3]=(__bf16)v0.w;
            o0[4]=(__bf16)v1.x; o0[5]=(__bf16)v1.y; o0[6]=(__bf16)v1.z; o0[7]=(__bf16)v1.w;
            o1[0]=(__bf16)v2.x; o1[1]=(__bf16)v2.y; o1[2]=(__bf16)v2.z; o1[3]=(__bf16)v2.w;
            o1[4]=(__bf16)v3.x; o1[5]=(__bf16)v3.y; o1[6]=(__bf16)v3.z; o1[7]=(__bf16)v3.w;
            *(bf16x8*)(xb + (size_t)t * HID + c0) = o0;
            *(bf16x8*)(xb + (size_t)t * HID + c0 + 8) = o1;
        }
        if (bid == 0 && tid < 128) {   // zero pad-row
            bf16x8 z8;
            #pragma unroll
            for (int j = 0; j < 8; ++j) z8[j] = (__bf16)0.f;
            *(bf16x8*)(xb + (size_t)T_TOKENS * HID + tid * 8) = z8;
        }

        float le[8] = {0.f, 0.f, 0.f, 0.f, 0.f, 0.f, 0.f, 0.f};
        float xv[16];
        xv[0]=v0.x; xv[1]=v0.y; xv[2]=v0.z; xv[3]=v0.w;
        xv[4]=v1.x; xv[5]=v1.y; xv[6]=v1.z; xv[7]=v1.w;
        xv[8]=v2.x; xv[9]=v2.y; xv[10]=v2.z; xv[11]=v2.w;
        xv[12]=v3.x; xv[13]=v3.y; xv[14]=v3.z; xv[15]=v3.w;
        #pragma unroll
        for (int j = 0; j < 16; ++j) {
            const float* gr = gw + (size_t)(c0 + j) * NEXP;
            float4 g0 = *(const float4*)gr;
            float4 g1 = *(const float4*)(gr + 4);
            le[0] += xv[j] * g0.x; le[1] += xv[j] * g0.y;
            le[2] += xv[j] * g0.z; le[3] += xv[j] * g0.w;
            le[4] += xv[j] * g1.x; le[5] += xv[j] * g1.y;
            le[6] += xv[j] * g1.z; le[7] += xv[j] * g1.w;
        }
        #pragma unroll
        for (int d = 1; d < 64; d <<= 1) {
            #pragma unroll
            for (int k = 0; k < 8; ++k) le[k] += __shfl_xor(le[k], d);
        }
        float m = le[0];
        #pragma unroll
        for (int k = 1; k < 8; ++k) m = fmaxf(m, le[k]);
        float pe[8]; float s = 0.f;
        #pragma unroll
        for (int k = 0; k < 8; ++k) { pe[k] = expf(le[k] - m); s += pe[k]; }
        int e1 = 0; float p1 = pe[0];
        #pragma unroll
        for (int k = 1; k < 8; ++k) if (pe[k] > p1) { p1 = pe[k]; e1 = k; }
        int e2 = -1; float p2 = -1.f;
        #pragma unroll
        for (int k = 0; k < 8; ++k) if (k != e1 && pe[k] > p2) { p2 = pe[k]; e2 = k; }
        if (lane == 0) {
            float inv = 1.0f / (p1 + p2);
            sel[t * 2 + 0] = e1; sel[t * 2 + 1] = e2;
            wt[t * 2 + 0] = p1 * inv; wt[t * 2 + 1] = p2 * inv;
        }
        return;
    }

    // ---- tcvt role: 4224 blocks x 2 tiles ----
    const int f   = bid - 512;
    const int z   = f / 176;           // 0..23
    const int rem = f % 176;
    const int bx  = rem / 16;          // 0..10
    const int by  = rem & 15;          // 0..15
    const int e   = z & 7;
    const float* in;
    __bf16* out;
    int R, C, rrA, ccA, rrB, ccB;
    if (z < 16) {
        R = HID; C = ISZ;
        rrA = rrB = by * 64;
        ccA = bx * 128; ccB = ccA + 64;
        in  = (z < 8 ? wg : wu)  + (size_t)e * R * C;
        out = (z < 8 ? wgT : wuT) + (size_t)e * R * C;
    } else {
        R = ISZ; C = HID;
        ccA = ccB = by * 64;
        rrA = bx * 128; rrB = rrA + 64;
        in  = wd  + (size_t)e * R * C;
        out = wdT + (size_t)e * R * C;
    }
    const int lr  = tid >> 4;          // 0..15
    const int lc4 = (tid & 15) * 4;

    auto loadcvt = [&](int buf, int rr, int cc) {
        #pragma unroll
        for (int p = 0; p < 4; ++p) {
            float4 v = *(const float4*)(in + (size_t)(rr + p * 16 + lr) * C + cc + lc4);
            bf16x4 w;
            w[0] = (__bf16)v.x; w[1] = (__bf16)v.y; w[2] = (__bf16)v.z; w[3] = (__bf16)v.w;
            *(bf16x4*)&tb[buf][p * 16 + lr][lc4] = w;
        }
    };
    auto storeT = [&](int buf, int rr, int cc) {
        #pragma unroll
        for (int q = 0; q < 2; ++q) {
            const int oc = (tid >> 3) + 32 * q;   // out row local (= in col)
            const int vs = (tid & 7) * 8;         // out col local (= in row) base
            bf16x8 w;
            #pragma unroll
            for (int j = 0; j < 8; ++j) w[j] = tb[buf][vs + j][oc];
            *(bf16x8*)(out + (size_t)(cc + oc) * R + rr + vs) = w;
        }
    };

    loadcvt(0, rrA, ccA);
    __syncthreads();
    loadcvt(1, rrB, ccB);   // tile-B loads fly under tile-A's LDS reads/stores
    storeT(0, rrA, ccA);
    __syncthreads();
    storeT(1, rrB, ccB);
}

// ---------------- Histogram + scan + assign + tile table (single block, 1024 thr) --------
__global__ __launch_bounds__(1024) void scan_assign_kernel(
    int* __restrict__ tiles,
    const int* __restrict__ sel, const float* __restrict__ wt,
    int* __restrict__ rtok, float* __restrict__ rwt, int* __restrict__ tok2row)
{
    __shared__ int hist[NEXP];
    __shared__ int soff[NEXP];
    __shared__ int scur[NEXP];
    if (threadIdx.x < NEXP) { hist[threadIdx.x] = 0; scur[threadIdx.x] = 0; }
    __syncthreads();
    for (int t = threadIdx.x; t < T_TOKENS; t += 1024) {
        atomicAdd(&hist[sel[t * 2 + 0]], 1);
        atomicAdd(&hist[sel[t * 2 + 1]], 1);
    }
    __syncthreads();
    if (threadIdx.x == 0) {
        int cur = 0, tix = 0;
        for (int e = 0; e < NEXP; ++e) {
            soff[e] = cur;
            int n64 = (hist[e] + 63) & ~63;            // 64-row tile alignment
            for (int rt = 0; rt * 64 < n64; ++rt)
                tiles[tix++] = (e << 16) | (cur + rt * 64);
            cur += n64;
        }
        for (; tix < TILES_MAX; ++tix) tiles[tix] = -1;
    }
    __syncthreads();
    for (int t = threadIdx.x; t < T_TOKENS; t += 1024) {
        #pragma unroll
        for (int k = 0; k < 2; ++k) {
            int e = sel[t * 2 + k];
            int pos = atomicAdd(&scur[e], 1);
            int row = soff[e] + pos;
            rtok[row] = t + 1;          // sentinel: 0 = pad row
            rwt[row] = wt[t * 2 + k];
            tok2row[t * 2 + k] = row;
        }
    }
}

// ---------------- FFN1: inter = silu(x@WgT') * (x@WuT') ----------------
// BM=64, BN=64(G)+64(U), BK=32, 32x32x16 MFMA, 4 waves 2x2 (each 32r x 32c of G AND U).
// 4-buf depth-3 counted-vmcnt pipeline (3 loads/stage, vmcnt(6)). 48 KB -> 3 blocks/CU.
__global__ __launch_bounds__(256) void ffn1_kernel(
    const __bf16* __restrict__ xb, const int* __restrict__ rtok,
    const __bf16* __restrict__ wgT, const __bf16* __restrict__ wuT,
    const int* __restrict__ tiles, __bf16* __restrict__ inter)
{
    // grid 1584 = 22 stripes x 72 tiles; XCD chunks of 198
    const int n  = blockIdx.x;
    const int nn = (n & 7) * 198 + (n >> 3);
    const int i0 = (nn / TILES_MAX) * 64;      // stripe 0..21
    const int tv = tiles[nn % TILES_MAX];
    if (tv < 0) return;
    const int e = tv >> 16;
    const int rowbase = tv & 0xFFFF;

    __shared__ __align__(16) __bf16 sA[4][64][32];  // 16 KB
    __shared__ __align__(16) __bf16 sG[4][64][32];  // 16 KB
    __shared__ __align__(16) __bf16 sU[4][64][32];  // 16 KB -> 48 KB

    const int lane = threadIdx.x & 63;
    const int wid  = threadIdx.x >> 6;
    const int wr = wid >> 1, wc = wid & 1;
    const int l31 = lane & 31;
    const int kg  = lane >> 5;                 // k-half 0/1

    // staging: gload16 covers 16 rows x 64B; lane: row = lane>>2, slot = lane&3.
    // slot s at row R holds global chunk s ^ ((R>>1)&3)  (involution).
    const int r16 = lane >> 2;
    const int cz  = (((lane & 3) ^ ((r16 >> 1) & 3)) * 8);
    const int rowA = rowbase + wid * 16 + r16;
    const int tokp = rtok[rowA];
    const int src  = tokp ? (tokp - 1) : T_TOKENS;     // pad rows -> zero row
    const __bf16* A0 = xb + (size_t)src * HID + cz;
    const size_t wb = (size_t)e * ISZ * HID + (size_t)(i0 + wid * 16 + r16) * HID + cz;
    const __bf16* G0 = wgT + wb;
    const __bf16* U0 = wuT + wb;

    f32x16 accG, accU;
    #pragma unroll
    for (int r = 0; r < 16; ++r) { accG[r] = 0.f; accU[r] = 0.f; }

    auto stage = [&](int b, int k0) {   // 3 gload16 per wave
        gload16(A0 + k0, &sA[b][wid * 16][0]);
        gload16(G0 + k0, &sG[b][wid * 16][0]);
        gload16(U0 + k0, &sU[b][wid * 16][0]);
    };
    auto compute = [&](int b) {
        #pragma unroll
        for (int s = 0; s < 2; ++s) {
            const int ch = ((2 * s + kg) ^ ((l31 >> 1) & 3)) * 8;
            bf16x8 a_ = *(const bf16x8*)&sA[b][wr * 32 + l31][ch];
            bf16x8 g_ = *(const bf16x8*)&sG[b][wc * 32 + l31][ch];
            bf16x8 u_ = *(const bf16x8*)&sU[b][wc * 32 + l31][ch];
            __builtin_amdgcn_s_setprio(1);
            accG = __builtin_amdgcn_mfma_f32_32x32x16_bf16(a_, g_, accG, 0, 0, 0);
            accU = __builtin_amdgcn_mfma_f32_32x32x16_bf16(a_, u_, accU, 0, 0, 0);
            __builtin_amdgcn_s_setprio(0);
        }
    };

    const int nIter = HID / 32;   // 32
    stage(0, 0);
    stage(1, 32);
    stage(2, 64);
    PIPE_BARRIER(6)               // stage0 landed; stages 1,2 (6 loads) in flight
    for (int i = 0; i < nIter; ++i) {
        int ks = (i + 3 < nIter) ? (i + 3) * 32 : 0;   // clamped dead stage keeps counts uniform
        stage((i + 3) & 3, ks);
        compute(i & 3);
        PIPE_BARRIER(6)           // stage(i+1) landed; newest 2 stages in flight
    }

    // epilogue: silu(G)*U -> bf16 inter (D: col = lane&31, row = (r&3)+8*(r>>2)+4*kg)
    const int base_row = rowbase + wr * 32;
    #pragma unroll
    for (int r = 0; r < 16; ++r) {
        float g = accG[r];
        float u = accU[r];
        float v = g / (1.0f + __expf(-g)) * u;
        int row = base_row + (r & 3) + 8 * (r >> 2) + 4 * kg;
        inter[(size_t)row * ISZ + i0 + wc * 32 + l31] = (__bf16)v;
    }
}

// ---------------- FFN2: y[row] = rwt[row] * (inter[row] @ WdT')  (no atomics) ----------------
// BM=64, BN=128, BK=32, 4 waves 2x2: wave = 32 rows x 64 cols (two 32-col MFMA tiles).
// 4-buf depth-3 counted-vmcnt (3 loads/stage, vmcnt(6)). 48 KB -> 3 blocks/CU.
__global__ __launch_bounds__(256) void ffn2_kernel(
    const __bf16* __restrict__ inter, const __bf16* __restrict__ wdT,
    const float* __restrict__ rwt, const int* __restrict__ tiles,
    float* __restrict__ y)
{
    // grid 576 = 8 stripes x 72 tiles; XCD chunks of 72
    const int n  = blockIdx.x;
    const int nn = (n & 7) * 72 + (n >> 3);
    const int n0 = (nn / TILES_MAX) * 128;     // stripe 0..7
    const int tv = tiles[nn % TILES_MAX];
    if (tv < 0) return;
    const int e = tv >> 16;
    const int rowbase = tv & 0xFFFF;

    __shared__ __align__(16) __bf16 sA[4][64][32];   // 16 KB
    __shared__ __align__(16) __bf16 sB[4][128][32];  // 32 KB -> 48 KB

    const int lane = threadIdx.x & 63;
    const int wid  = threadIdx.x >> 6;
    const int wr = wid >> 1, wc = wid & 1;
    const int l31 = lane & 31;
    const int kg  = lane >> 5;

    const int r16 = lane >> 2;
    const int cz  = (((lane & 3) ^ ((r16 >> 1) & 3)) * 8);
    const __bf16* A0 = inter + (size_t)(rowbase + wid * 16 + r16) * ISZ + cz;
    const __bf16* B0 = wdT + (size_t)e * HID * ISZ + (size_t)(n0 + wid * 32 + r16) * ISZ + cz;
    const size_t rstepB = (size_t)16 * ISZ;

    f32x16 acc[2];
    #pragma unroll
    for (int q = 0; q < 2; ++q)
        #pragma unroll
        for (int r = 0; r < 16; ++r) acc[q][r] = 0.f;

    auto stage = [&](int b, int k0) {   // 3 gload16 per wave
        gload16(A0 + k0,          &sA[b][wid * 16][0]);
        gload16(B0 + k0,          &sB[b][wid * 32][0]);
        gload16(B0 + k0 + rstepB, &sB[b][wid * 32 + 16][0]);
    };
    auto compute = [&](int b) {
        #pragma unroll
        for (int s = 0; s < 2; ++s) {
            const int ch = ((2 * s + kg) ^ ((l31 >> 1) & 3)) * 8;
            bf16x8 a_ = *(const bf16x8*)&sA[b][wr * 32 + l31][ch];
            bf16x8 b0 = *(const bf16x8*)&sB[b][wc * 64 + l31][ch];
            bf16x8 b1 = *(const bf16x8*)&sB[b][wc * 64 + 32 + l31][ch];
            __builtin_amdgcn_s_setprio(1);
            acc[0] = __builtin_amdgcn_mfma_f32_32x32x16_bf16(a_, b0, acc[0], 0, 0, 0);
            acc[1] = __builtin_amdgcn_mfma_f32_32x32x16_bf16(a_, b1, acc[1], 0, 0, 0);
            __builtin_amdgcn_s_setprio(0);
        }
    };

    const int nIter = ISZ / 32;   // 44
    stage(0, 0);
    stage(1, 32);
    stage(2, 64);
    PIPE_BARRIER(6)
    for (int i = 0; i < nIter; ++i) {
        int ks = (i + 3 < nIter) ? (i + 3) * 32 : 0;
        stage((i + 3) & 3, ks);
        compute(i & 3);
        PIPE_BARRIER(6)
    }

    const int base_row = rowbase + wr * 32;
    #pragma unroll
    for (int q = 0; q < 2; ++q) {
        const int col = n0 + wc * 64 + q * 32 + l31;
        #pragma unroll
        for (int r = 0; r < 16; ++r) {
            int row = base_row + (r & 3) + 8 * (r >> 2) + 4 * kg;
            y[(size_t)row * HID + col] = rwt[row] * acc[q][r];
        }
    }
}

// ---------------- Combine: out[t] = y[row0(t)] + y[row1(t)] ----------------
__global__ __launch_bounds__(256) void combine_kernel(
    const float* __restrict__ y, const int* __restrict__ tok2row, float* __restrict__ out)
{
    const int idx = blockIdx.x * 256 + threadIdx.x;
    const int t = idx >> 8;
    const int c = (idx & 255) * 4;
    const int r0 = tok2row[t * 2];
    const int r1 = tok2row[t * 2 + 1];
    float4 a = *(const float4*)(y + (size_t)r0 * HID + c);
    float4 b = *(const float4*)(y + (size_t)r1 * HID + c);
    float4 o = {a.x + b.x, a.y + b.y, a.z + b.z, a.w + b.w};
    *(float4*)(out + (size_t)t * HID + c) = o;
}

extern "C" void kernel_launch(void* const* d_in, const int* in_sizes, int n_in,
                              void* d_out, int out_size, void* d_ws, size_t ws_size,
                              hipStream_t stream) {
    const float* x  = (const float*)d_in[0];
    const float* gw = (const float*)d_in[1];
    const float* wg = (const float*)d_in[2];
    const float* wu = (const float*)d_in[3];
    const float* wd = (const float*)d_in[4];
    float* out = (float*)d_out;

    char* ws = (char*)d_ws;
    int*    tiles   = (int*)(ws + 64);           // 72 ints
    int*    sel     = (int*)(ws + 1024);         // 4096 ints
    float*  wtp     = (float*)(ws + 17408);      // 4096 f32
    int*    rtok    = (int*)(ws + 33792);        // 4608 ints
    float*  rwt     = (float*)(ws + 52224);      // 4608 f32
    int*    tok2row = (int*)(ws + 70656);        // 4096 ints -> ends 87040
    __bf16* xb      = (__bf16*)(ws + 87040);     // 2049*1024 bf16 = 4.20 MB
    __bf16* inter   = (__bf16*)(ws + 4283648);   // 4608*1408 bf16 = 12.98 MB
    __bf16* wgT     = (__bf16*)(ws + 17260032);  // 23.07 MB
    __bf16* wuT     = (__bf16*)(ws + 40328704);  // 23.07 MB
    __bf16* wdT     = (__bf16*)(ws + 63397376);  // 23.07 MB -> ends 86.5 MB
    float*  y       = (float*)wgT;               // alias: wgT dead after ffn1 (18.9 <= 23.07 MB)

    // zero: tiles + rtok (sentinel 0 = pad) + rwt + headers
    hipMemsetAsync(ws, 0, 87040, stream);

    prep_kernel<<<4736, 256, 0, stream>>>(x, gw, sel, wtp, xb, wg, wu, wd, wgT, wuT, wdT);
    scan_assign_kernel<<<1, 1024, 0, stream>>>(tiles, sel, wtp, rtok, rwt, tok2row);

    ffn1_kernel<<<22 * TILES_MAX, 256, 0, stream>>>(xb, rtok, wgT, wuT, tiles, inter);  // 1584
    ffn2_kernel<<<8 * TILES_MAX, 256, 0, stream>>>(inter, wdT, rwt, tiles, y);          // 576
    combine_kernel<<<(T_TOKENS * HID / 4) / 256, 256, 0, stream>>>(y, tok2row, out);
}

// Round 24
// 143.041 us; speedup vs baseline: 1.0828x; 1.0100x over previous
//
#include <hip/hip_runtime.h>
#include <hip/hip_bf16.h>

#define T_TOKENS 2048
#define HID 1024
#define ISZ 1408
#define NEXP 8
#define TILES_MAX 72    // sum ceil(cnt_e/64) <= 4096/64 + 8 = 72

typedef __bf16 bf16x8 __attribute__((ext_vector_type(8)));
typedef __bf16 bf16x4 __attribute__((ext_vector_type(4)));
typedef float  f32x16 __attribute__((ext_vector_type(16)));

__device__ __forceinline__ void gload16(const void* g, void* l) {
    __builtin_amdgcn_global_load_lds(
        (const __attribute__((address_space(1))) void*)g,
        (__attribute__((address_space(3))) void*)l,
        16, 0, 0);
}

// counted-vmcnt barrier: newest N loads may stay in flight; everything older done.
#define PIPE_BARRIER(N)                                              \
    asm volatile("s_waitcnt vmcnt(" #N ") lgkmcnt(0)" ::: "memory"); \
    __builtin_amdgcn_sched_barrier(0);                               \
    __builtin_amdgcn_s_barrier();                                    \
    __builtin_amdgcn_sched_barrier(0);

// ---------------- prep: router role (blocks 0..511, HEAD) + wg/wu tcvt (512..3327) -------
// router: ZERO LDS, one token/wave (R19-verified). tcvt: 2x 64x64 tiles/block (R16 path).
// wd conversion is DEFERRED: it rides in ffn1's grid (ffn1 doesn't read wdT; ffn2 launches
// after ffn1 completes, so wdT is ready by stream order).
__global__ __launch_bounds__(256) void prep_kernel(
    const float* __restrict__ x, const float* __restrict__ gw,
    int* __restrict__ sel, float* __restrict__ wt, __bf16* __restrict__ xb,
    const float* __restrict__ wg, const float* __restrict__ wu,
    __bf16* __restrict__ wgT, __bf16* __restrict__ wuT)
{
    __shared__ __bf16 tb[2][64][70];   // 17.9 KB (tcvt role; router blocks leave it unused)
    const int bid = blockIdx.x;
    const int tid = threadIdx.x;

    if (bid < 512) {
        // ---- router role ----
        const int wave = tid >> 6;
        const int lane = tid & 63;
        const int t = bid * 4 + wave;
        const float* xr = x + (size_t)t * HID;

        const int c0 = lane * 16;
        float4 v0 = *(const float4*)(xr + c0);
        float4 v1 = *(const float4*)(xr + c0 + 4);
        float4 v2 = *(const float4*)(xr + c0 + 8);
        float4 v3 = *(const float4*)(xr + c0 + 12);
        {
            bf16x8 o0, o1;
            o0[0]=(__bf16)v0.x; o0[1]=(__bf16)v0.y; o0[2]=(__bf16)v0.z; o0[3]=(__bf16)v0.w;
            o0[4]=(__bf16)v1.x; o0[5]=(__bf16)v1.y; o0[6]=(__bf16)v1.z; o0[7]=(__bf16)v1.w;
            o1[0]=(__bf16)v2.x; o1[1]=(__bf16)v2.y; o1[2]=(__bf16)v2.z; o1[3]=(__bf16)v2.w;
            o1[4]=(__bf16)v3.x; o1[5]=(__bf16)v3.y; o1[6]=(__bf16)v3.z; o1[7]=(__bf16)v3.w;
            *(bf16x8*)(xb + (size_t)t * HID + c0) = o0;
            *(bf16x8*)(xb + (size_t)t * HID + c0 + 8) = o1;
        }
        if (bid == 0 && tid < 128) {   // zero pad-row
            bf16x8 z8;
            #pragma unroll
            for (int j = 0; j < 8; ++j) z8[j] = (__bf16)0.f;
            *(bf16x8*)(xb + (size_t)T_TOKENS * HID + tid * 8) = z8;
        }

        float le[8] = {0.f, 0.f, 0.f, 0.f, 0.f, 0.f, 0.f, 0.f};
        float xv[16];
        xv[0]=v0.x; xv[1]=v0.y; xv[2]=v0.z; xv[3]=v0.w;
        xv[4]=v1.x; xv[5]=v1.y; xv[6]=v1.z; xv[7]=v1.w;
        xv[8]=v2.x; xv[9]=v2.y; xv[10]=v2.z; xv[11]=v2.w;
        xv[12]=v3.x; xv[13]=v3.y; xv[14]=v3.z; xv[15]=v3.w;
        #pragma unroll
        for (int j = 0; j < 16; ++j) {
            const float* gr = gw + (size_t)(c0 + j) * NEXP;
            float4 g0 = *(const float4*)gr;
            float4 g1 = *(const float4*)(gr + 4);
            le[0] += xv[j] * g0.x; le[1] += xv[j] * g0.y;
            le[2] += xv[j] * g0.z; le[3] += xv[j] * g0.w;
            le[4] += xv[j] * g1.x; le[5] += xv[j] * g1.y;
            le[6] += xv[j] * g1.z; le[7] += xv[j] * g1.w;
        }
        #pragma unroll
        for (int d = 1; d < 64; d <<= 1) {
            #pragma unroll
            for (int k = 0; k < 8; ++k) le[k] += __shfl_xor(le[k], d);
        }
        float m = le[0];
        #pragma unroll
        for (int k = 1; k < 8; ++k) m = fmaxf(m, le[k]);
        float pe[8]; float s = 0.f;
        #pragma unroll
        for (int k = 0; k < 8; ++k) { pe[k] = expf(le[k] - m); s += pe[k]; }
        int e1 = 0; float p1 = pe[0];
        #pragma unroll
        for (int k = 1; k < 8; ++k) if (pe[k] > p1) { p1 = pe[k]; e1 = k; }
        int e2 = -1; float p2 = -1.f;
        #pragma unroll
        for (int k = 0; k < 8; ++k) if (k != e1 && pe[k] > p2) { p2 = pe[k]; e2 = k; }
        if (lane == 0) {
            float inv = 1.0f / (p1 + p2);
            sel[t * 2 + 0] = e1; sel[t * 2 + 1] = e2;
            wt[t * 2 + 0] = p1 * inv; wt[t * 2 + 1] = p2 * inv;
        }
        return;
    }

    // ---- tcvt role: 2816 blocks x 2 tiles (wg, wu only) ----
    const int f   = bid - 512;
    const int z   = f / 176;           // 0..15
    const int rem = f % 176;
    const int bx  = rem / 16;          // 0..10
    const int by  = rem & 15;          // 0..15
    const int e   = z & 7;
    const int R = HID, C = ISZ;
    const float* in = (z < 8 ? wg : wu) + (size_t)e * R * C;
    __bf16* out = (z < 8 ? wgT : wuT) + (size_t)e * R * C;
    const int rrA = by * 64, rrB = rrA;
    const int ccA = bx * 128, ccB = ccA + 64;
    const int lr  = tid >> 4;          // 0..15
    const int lc4 = (tid & 15) * 4;

    auto loadcvt = [&](int buf, int rr, int cc) {
        #pragma unroll
        for (int p = 0; p < 4; ++p) {
            float4 v = *(const float4*)(in + (size_t)(rr + p * 16 + lr) * C + cc + lc4);
            bf16x4 w;
            w[0] = (__bf16)v.x; w[1] = (__bf16)v.y; w[2] = (__bf16)v.z; w[3] = (__bf16)v.w;
            *(bf16x4*)&tb[buf][p * 16 + lr][lc4] = w;
        }
    };
    auto storeT = [&](int buf, int rr, int cc) {
        #pragma unroll
        for (int q = 0; q < 2; ++q) {
            const int oc = (tid >> 3) + 32 * q;
            const int vs = (tid & 7) * 8;
            bf16x8 w;
            #pragma unroll
            for (int j = 0; j < 8; ++j) w[j] = tb[buf][vs + j][oc];
            *(bf16x8*)(out + (size_t)(cc + oc) * R + rr + vs) = w;
        }
    };

    loadcvt(0, rrA, ccA);
    __syncthreads();
    loadcvt(1, rrB, ccB);
    storeT(0, rrA, ccA);
    __syncthreads();
    storeT(1, rrB, ccB);
}

// ---------------- Histogram + scan + assign + tile table (single block, 1024 thr) --------
__global__ __launch_bounds__(1024) void scan_assign_kernel(
    int* __restrict__ tiles,
    const int* __restrict__ sel, const float* __restrict__ wt,
    int* __restrict__ rtok, float* __restrict__ rwt, int* __restrict__ tok2row)
{
    __shared__ int hist[NEXP];
    __shared__ int soff[NEXP];
    __shared__ int scur[NEXP];
    if (threadIdx.x < NEXP) { hist[threadIdx.x] = 0; scur[threadIdx.x] = 0; }
    __syncthreads();
    for (int t = threadIdx.x; t < T_TOKENS; t += 1024) {
        atomicAdd(&hist[sel[t * 2 + 0]], 1);
        atomicAdd(&hist[sel[t * 2 + 1]], 1);
    }
    __syncthreads();
    if (threadIdx.x == 0) {
        int cur = 0, tix = 0;
        for (int e = 0; e < NEXP; ++e) {
            soff[e] = cur;
            int n64 = (hist[e] + 63) & ~63;            // 64-row tile alignment
            for (int rt = 0; rt * 64 < n64; ++rt)
                tiles[tix++] = (e << 16) | (cur + rt * 64);
            cur += n64;
        }
        for (; tix < TILES_MAX; ++tix) tiles[tix] = -1;
    }
    __syncthreads();
    for (int t = threadIdx.x; t < T_TOKENS; t += 1024) {
        #pragma unroll
        for (int k = 0; k < 2; ++k) {
            int e = sel[t * 2 + k];
            int pos = atomicAdd(&scur[e], 1);
            int row = soff[e] + pos;
            rtok[row] = t + 1;          // sentinel: 0 = pad row
            rwt[row] = wt[t * 2 + k];
            tok2row[t * 2 + k] = row;
        }
    }
}

// ---------------- FFN1 + deferred wd-cvt rider ----------------
// blocks 0..1583: FFN1 (BM=64, BN=64+64, BK=32, 32x32x16, 4-buf depth-3 counted-vmcnt).
// blocks 1584..2991: wd transpose-convert rider (runs in ffn1's idle memory bandwidth;
// wdT complete before ffn2 by stream order). Shared LDS union (48 KB).
__global__ __launch_bounds__(256) void ffn1_kernel(
    const __bf16* __restrict__ xb, const int* __restrict__ rtok,
    const __bf16* __restrict__ wgT, const __bf16* __restrict__ wuT,
    const int* __restrict__ tiles, __bf16* __restrict__ inter,
    const float* __restrict__ wd, __bf16* __restrict__ wdT)
{
    __shared__ __align__(16) char smem[49152];   // union: ffn1 48 KB | tcvt 17.9 KB
    const int n   = blockIdx.x;
    const int tid = threadIdx.x;

    if (n >= 22 * TILES_MAX) {
        // ---- wd-cvt rider: 1408 blocks x 2 tiles ----
        auto tb = (__bf16 (*)[64][70])smem;
        const int f   = n - 22 * TILES_MAX;
        const int e   = f / 176;
        const int rem = f % 176;
        const int bx  = rem / 16;          // 0..10
        const int by  = rem & 15;          // 0..15
        const int R = ISZ, C = HID;
        const float* in = wd + (size_t)e * R * C;
        __bf16* out = wdT + (size_t)e * R * C;
        const int ccA = by * 64, ccB = ccA;
        const int rrA = bx * 128, rrB = rrA + 64;
        const int lr  = tid >> 4;
        const int lc4 = (tid & 15) * 4;

        auto loadcvt = [&](int buf, int rr, int cc) {
            #pragma unroll
            for (int p = 0; p < 4; ++p) {
                float4 v = *(const float4*)(in + (size_t)(rr + p * 16 + lr) * C + cc + lc4);
                bf16x4 w;
                w[0] = (__bf16)v.x; w[1] = (__bf16)v.y; w[2] = (__bf16)v.z; w[3] = (__bf16)v.w;
                *(bf16x4*)&tb[buf][p * 16 + lr][lc4] = w;
            }
        };
        auto storeT = [&](int buf, int rr, int cc) {
            #pragma unroll
            for (int q = 0; q < 2; ++q) {
                const int oc = (tid >> 3) + 32 * q;
                const int vs = (tid & 7) * 8;
                bf16x8 w;
                #pragma unroll
                for (int j = 0; j < 8; ++j) w[j] = tb[buf][vs + j][oc];
                *(bf16x8*)(out + (size_t)(cc + oc) * R + rr + vs) = w;
            }
        };

        loadcvt(0, rrA, ccA);
        __syncthreads();
        loadcvt(1, rrB, ccB);
        storeT(0, rrA, ccA);
        __syncthreads();
        storeT(1, rrB, ccB);
        return;
    }

    // ---- FFN1 role (grid 1584 = 22 stripes x 72 tiles; XCD chunks of 198) ----
    auto sA = (__bf16 (*)[64][32])(smem);            // [4][64][32]
    auto sG = (__bf16 (*)[64][32])(smem + 16384);
    auto sU = (__bf16 (*)[64][32])(smem + 32768);

    const int nn = (n & 7) * 198 + (n >> 3);
    const int i0 = (nn / TILES_MAX) * 64;      // stripe 0..21
    const int tv = tiles[nn % TILES_MAX];
    if (tv < 0) return;
    const int e = tv >> 16;
    const int rowbase = tv & 0xFFFF;

    const int lane = tid & 63;
    const int wid  = tid >> 6;
    const int wr = wid >> 1, wc = wid & 1;
    const int l31 = lane & 31;
    const int kg  = lane >> 5;                 // k-half 0/1

    // staging: gload16 covers 16 rows x 64B; lane: row = lane>>2, slot = lane&3.
    // slot s at row R holds global chunk s ^ ((R>>1)&3)  (involution).
    const int r16 = lane >> 2;
    const int cz  = (((lane & 3) ^ ((r16 >> 1) & 3)) * 8);
    const int rowA = rowbase + wid * 16 + r16;
    const int tokp = rtok[rowA];
    const int src  = tokp ? (tokp - 1) : T_TOKENS;     // pad rows -> zero row
    const __bf16* A0 = xb + (size_t)src * HID + cz;
    const size_t wb = (size_t)e * ISZ * HID + (size_t)(i0 + wid * 16 + r16) * HID + cz;
    const __bf16* G0 = wgT + wb;
    const __bf16* U0 = wuT + wb;

    f32x16 accG, accU;
    #pragma unroll
    for (int r = 0; r < 16; ++r) { accG[r] = 0.f; accU[r] = 0.f; }

    auto stage = [&](int b, int k0) {   // 3 gload16 per wave
        gload16(A0 + k0, &sA[b][wid * 16][0]);
        gload16(G0 + k0, &sG[b][wid * 16][0]);
        gload16(U0 + k0, &sU[b][wid * 16][0]);
    };
    auto compute = [&](int b) {
        #pragma unroll
        for (int s = 0; s < 2; ++s) {
            const int ch = ((2 * s + kg) ^ ((l31 >> 1) & 3)) * 8;
            bf16x8 a_ = *(const bf16x8*)&sA[b][wr * 32 + l31][ch];
            bf16x8 g_ = *(const bf16x8*)&sG[b][wc * 32 + l31][ch];
            bf16x8 u_ = *(const bf16x8*)&sU[b][wc * 32 + l31][ch];
            __builtin_amdgcn_s_setprio(1);
            accG = __builtin_amdgcn_mfma_f32_32x32x16_bf16(a_, g_, accG, 0, 0, 0);
            accU = __builtin_amdgcn_mfma_f32_32x32x16_bf16(a_, u_, accU, 0, 0, 0);
            __builtin_amdgcn_s_setprio(0);
        }
    };

    const int nIter = HID / 32;   // 32
    stage(0, 0);
    stage(1, 32);
    stage(2, 64);
    PIPE_BARRIER(6)               // stage0 landed; stages 1,2 (6 loads) in flight
    for (int i = 0; i < nIter; ++i) {
        int ks = (i + 3 < nIter) ? (i + 3) * 32 : 0;   // clamped dead stage keeps counts uniform
        stage((i + 3) & 3, ks);
        compute(i & 3);
        PIPE_BARRIER(6)           // stage(i+1) landed; newest 2 stages in flight
    }

    // epilogue: silu(G)*U -> bf16 inter (D: col = lane&31, row = (r&3)+8*(r>>2)+4*kg)
    const int base_row = rowbase + wr * 32;
    #pragma unroll
    for (int r = 0; r < 16; ++r) {
        float g = accG[r];
        float u = accU[r];
        float v = g / (1.0f + __expf(-g)) * u;
        int row = base_row + (r & 3) + 8 * (r >> 2) + 4 * kg;
        inter[(size_t)row * ISZ + i0 + wc * 32 + l31] = (__bf16)v;
    }
}

// ---------------- FFN2: y[row] = rwt[row] * (inter[row] @ WdT')  (no atomics) ----------------
// BM=64, BN=128, BK=32, 4 waves 2x2: wave = 32 rows x 64 cols (two 32-col MFMA tiles).
// 4-buf depth-3 counted-vmcnt (3 loads/stage, vmcnt(6)). 48 KB -> 3 blocks/CU.
__global__ __launch_bounds__(256) void ffn2_kernel(
    const __bf16* __restrict__ inter, const __bf16* __restrict__ wdT,
    const float* __restrict__ rwt, const int* __restrict__ tiles,
    float* __restrict__ y)
{
    // grid 576 = 8 stripes x 72 tiles; XCD chunks of 72
    const int n  = blockIdx.x;
    const int nn = (n & 7) * 72 + (n >> 3);
    const int n0 = (nn / TILES_MAX) * 128;     // stripe 0..7
    const int tv = tiles[nn % TILES_MAX];
    if (tv < 0) return;
    const int e = tv >> 16;
    const int rowbase = tv & 0xFFFF;

    __shared__ __align__(16) __bf16 sA[4][64][32];   // 16 KB
    __shared__ __align__(16) __bf16 sB[4][128][32];  // 32 KB -> 48 KB

    const int lane = threadIdx.x & 63;
    const int wid  = threadIdx.x >> 6;
    const int wr = wid >> 1, wc = wid & 1;
    const int l31 = lane & 31;
    const int kg  = lane >> 5;

    const int r16 = lane >> 2;
    const int cz  = (((lane & 3) ^ ((r16 >> 1) & 3)) * 8);
    const __bf16* A0 = inter + (size_t)(rowbase + wid * 16 + r16) * ISZ + cz;
    const __bf16* B0 = wdT + (size_t)e * HID * ISZ + (size_t)(n0 + wid * 32 + r16) * ISZ + cz;
    const size_t rstepB = (size_t)16 * ISZ;

    f32x16 acc[2];
    #pragma unroll
    for (int q = 0; q < 2; ++q)
        #pragma unroll
        for (int r = 0; r < 16; ++r) acc[q][r] = 0.f;

    auto stage = [&](int b, int k0) {   // 3 gload16 per wave
        gload16(A0 + k0,          &sA[b][wid * 16][0]);
        gload16(B0 + k0,          &sB[b][wid * 32][0]);
        gload16(B0 + k0 + rstepB, &sB[b][wid * 32 + 16][0]);
    };
    auto compute = [&](int b) {
        #pragma unroll
        for (int s = 0; s < 2; ++s) {
            const int ch = ((2 * s + kg) ^ ((l31 >> 1) & 3)) * 8;
            bf16x8 a_ = *(const bf16x8*)&sA[b][wr * 32 + l31][ch];
            bf16x8 b0 = *(const bf16x8*)&sB[b][wc * 64 + l31][ch];
            bf16x8 b1 = *(const bf16x8*)&sB[b][wc * 64 + 32 + l31][ch];
            __builtin_amdgcn_s_setprio(1);
            acc[0] = __builtin_amdgcn_mfma_f32_32x32x16_bf16(a_, b0, acc[0], 0, 0, 0);
            acc[1] = __builtin_amdgcn_mfma_f32_32x32x16_bf16(a_, b1, acc[1], 0, 0, 0);
            __builtin_amdgcn_s_setprio(0);
        }
    };

    const int nIter = ISZ / 32;   // 44
    stage(0, 0);
    stage(1, 32);
    stage(2, 64);
    PIPE_BARRIER(6)
    for (int i = 0; i < nIter; ++i) {
        int ks = (i + 3 < nIter) ? (i + 3) * 32 : 0;
        stage((i + 3) & 3, ks);
        compute(i & 3);
        PIPE_BARRIER(6)
    }

    const int base_row = rowbase + wr * 32;
    #pragma unroll
    for (int q = 0; q < 2; ++q) {
        const int col = n0 + wc * 64 + q * 32 + l31;
        #pragma unroll
        for (int r = 0; r < 16; ++r) {
            int row = base_row + (r & 3) + 8 * (r >> 2) + 4 * kg;
            y[(size_t)row * HID + col] = rwt[row] * acc[q][r];
        }
    }
}

// ---------------- Combine: out[t] = y[row0(t)] + y[row1(t)] ----------------
__global__ __launch_bounds__(256) void combine_kernel(
    const float* __restrict__ y, const int* __restrict__ tok2row, float* __restrict__ out)
{
    const int idx = blockIdx.x * 256 + threadIdx.x;
    const int t = idx >> 8;
    const int c = (idx & 255) * 4;
    const int r0 = tok2row[t * 2];
    const int r1 = tok2row[t * 2 + 1];
    float4 a = *(const float4*)(y + (size_t)r0 * HID + c);
    float4 b = *(const float4*)(y + (size_t)r1 * HID + c);
    float4 o = {a.x + b.x, a.y + b.y, a.z + b.z, a.w + b.w};
    *(float4*)(out + (size_t)t * HID + c) = o;
}

extern "C" void kernel_launch(void* const* d_in, const int* in_sizes, int n_in,
                              void* d_out, int out_size, void* d_ws, size_t ws_size,
                              hipStream_t stream) {
    const float* x  = (const float*)d_in[0];
    const float* gw = (const float*)d_in[1];
    const float* wg = (const float*)d_in[2];
    const float* wu = (const float*)d_in[3];
    const float* wd = (const float*)d_in[4];
    float* out = (float*)d_out;

    char* ws = (char*)d_ws;
    int*    tiles   = (int*)(ws + 64);           // 72 ints
    int*    sel     = (int*)(ws + 1024);         // 4096 ints
    float*  wtp     = (float*)(ws + 17408);      // 4096 f32
    int*    rtok    = (int*)(ws + 33792);        // 4608 ints
    float*  rwt     = (float*)(ws + 52224);      // 4608 f32
    int*    tok2row = (int*)(ws + 70656);        // 4096 ints -> ends 87040
    __bf16* xb      = (__bf16*)(ws + 87040);     // 2049*1024 bf16 = 4.20 MB
    __bf16* inter   = (__bf16*)(ws + 4283648);   // 4608*1408 bf16 = 12.98 MB
    __bf16* wgT     = (__bf16*)(ws + 17260032);  // 23.07 MB
    __bf16* wuT     = (__bf16*)(ws + 40328704);  // 23.07 MB
    __bf16* wdT     = (__bf16*)(ws + 63397376);  // 23.07 MB -> ends 86.5 MB
    float*  y       = (float*)wgT;               // alias: wgT dead after ffn1 (18.9 <= 23.07 MB)

    // zero: tiles + rtok (sentinel 0 = pad) + rwt + headers
    hipMemsetAsync(ws, 0, 87040, stream);

    prep_kernel<<<3328, 256, 0, stream>>>(x, gw, sel, wtp, xb, wg, wu, wgT, wuT);
    scan_assign_kernel<<<1, 1024, 0, stream>>>(tiles, sel, wtp, rtok, rwt, tok2row);

    // ffn1 (1584) + deferred wd-cvt rider (1408)
    ffn1_kernel<<<22 * TILES_MAX + 1408, 256, 0, stream>>>(
        xb, rtok, wgT, wuT, tiles, inter, wd, wdT);
    ffn2_kernel<<<8 * TILES_MAX, 256, 0, stream>>>(inter, wdT, rwt, tiles, y);          // 576
    combine_kernel<<<(T_TOKENS * HID / 4) / 256, 256, 0, stream>>>(y, tok2row, out);
}

// Round 25
// 133.923 us; speedup vs baseline: 1.1565x; 1.0681x over previous
//
#include <hip/hip_runtime.h>
#include <hip/hip_bf16.h>

#define T_TOKENS 2048
#define HID 1024
#define ISZ 1408
#define NEXP 8
#define TILES_MAX 72    // sum ceil(cnt_e/64) <= 4096/64 + 8 = 72

typedef __bf16 bf16x8 __attribute__((ext_vector_type(8)));
typedef __bf16 bf16x4 __attribute__((ext_vector_type(4)));
typedef float  f32x16 __attribute__((ext_vector_type(16)));

__device__ __forceinline__ void gload16(const void* g, void* l) {
    __builtin_amdgcn_global_load_lds(
        (const __attribute__((address_space(1))) void*)g,
        (__attribute__((address_space(3))) void*)l,
        16, 0, 0);
}

// counted-vmcnt barrier: newest N loads may stay in flight; everything older done.
#define PIPE_BARRIER(N)                                              \
    asm volatile("s_waitcnt vmcnt(" #N ") lgkmcnt(0)" ::: "memory"); \
    __builtin_amdgcn_sched_barrier(0);                               \
    __builtin_amdgcn_s_barrier();                                    \
    __builtin_amdgcn_sched_barrier(0);

// ---------------- prep: router role (blocks 0..511, HEAD) + wg/wu tcvt (512..3327) -------
__global__ __launch_bounds__(256) void prep_kernel(
    const float* __restrict__ x, const float* __restrict__ gw,
    int* __restrict__ sel, float* __restrict__ wt, __bf16* __restrict__ xb,
    const float* __restrict__ wg, const float* __restrict__ wu,
    __bf16* __restrict__ wgT, __bf16* __restrict__ wuT)
{
    __shared__ __bf16 tb[2][64][70];   // 17.9 KB (tcvt role; router blocks leave it unused)
    const int bid = blockIdx.x;
    const int tid = threadIdx.x;

    if (bid < 512) {
        // ---- router role (R19-verified zero-LDS math) ----
        const int wave = tid >> 6;
        const int lane = tid & 63;
        const int t = bid * 4 + wave;
        const float* xr = x + (size_t)t * HID;

        const int c0 = lane * 16;
        float4 v0 = *(const float4*)(xr + c0);
        float4 v1 = *(const float4*)(xr + c0 + 4);
        float4 v2 = *(const float4*)(xr + c0 + 8);
        float4 v3 = *(const float4*)(xr + c0 + 12);
        {
            bf16x8 o0, o1;
            o0[0]=(__bf16)v0.x; o0[1]=(__bf16)v0.y; o0[2]=(__bf16)v0.z; o0[3]=(__bf16)v0.w;
            o0[4]=(__bf16)v1.x; o0[5]=(__bf16)v1.y; o0[6]=(__bf16)v1.z; o0[7]=(__bf16)v1.w;
            o1[0]=(__bf16)v2.x; o1[1]=(__bf16)v2.y; o1[2]=(__bf16)v2.z; o1[3]=(__bf16)v2.w;
            o1[4]=(__bf16)v3.x; o1[5]=(__bf16)v3.y; o1[6]=(__bf16)v3.z; o1[7]=(__bf16)v3.w;
            *(bf16x8*)(xb + (size_t)t * HID + c0) = o0;
            *(bf16x8*)(xb + (size_t)t * HID + c0 + 8) = o1;
        }
        if (bid == 0 && tid < 128) {   // zero pad-row
            bf16x8 z8;
            #pragma unroll
            for (int j = 0; j < 8; ++j) z8[j] = (__bf16)0.f;
            *(bf16x8*)(xb + (size_t)T_TOKENS * HID + tid * 8) = z8;
        }

        float le[8] = {0.f, 0.f, 0.f, 0.f, 0.f, 0.f, 0.f, 0.f};
        float xv[16];
        xv[0]=v0.x; xv[1]=v0.y; xv[2]=v0.z; xv[3]=v0.w;
        xv[4]=v1.x; xv[5]=v1.y; xv[6]=v1.z; xv[7]=v1.w;
        xv[8]=v2.x; xv[9]=v2.y; xv[10]=v2.z; xv[11]=v2.w;
        xv[12]=v3.x; xv[13]=v3.y; xv[14]=v3.z; xv[15]=v3.w;
        #pragma unroll
        for (int j = 0; j < 16; ++j) {
            const float* gr = gw + (size_t)(c0 + j) * NEXP;
            float4 g0 = *(const float4*)gr;
            float4 g1 = *(const float4*)(gr + 4);
            le[0] += xv[j] * g0.x; le[1] += xv[j] * g0.y;
            le[2] += xv[j] * g0.z; le[3] += xv[j] * g0.w;
            le[4] += xv[j] * g1.x; le[5] += xv[j] * g1.y;
            le[6] += xv[j] * g1.z; le[7] += xv[j] * g1.w;
        }
        #pragma unroll
        for (int d = 1; d < 64; d <<= 1) {
            #pragma unroll
            for (int k = 0; k < 8; ++k) le[k] += __shfl_xor(le[k], d);
        }
        float m = le[0];
        #pragma unroll
        for (int k = 1; k < 8; ++k) m = fmaxf(m, le[k]);
        float pe[8]; float s = 0.f;
        #pragma unroll
        for (int k = 0; k < 8; ++k) { pe[k] = expf(le[k] - m); s += pe[k]; }
        int e1 = 0; float p1 = pe[0];
        #pragma unroll
        for (int k = 1; k < 8; ++k) if (pe[k] > p1) { p1 = pe[k]; e1 = k; }
        int e2 = -1; float p2 = -1.f;
        #pragma unroll
        for (int k = 0; k < 8; ++k) if (k != e1 && pe[k] > p2) { p2 = pe[k]; e2 = k; }
        if (lane == 0) {
            float inv = 1.0f / (p1 + p2);
            sel[t * 2 + 0] = e1; sel[t * 2 + 1] = e2;
            wt[t * 2 + 0] = p1 * inv; wt[t * 2 + 1] = p2 * inv;
        }
        return;
    }

    // ---- tcvt role: 2816 blocks x 2 tiles (wg, wu only) ----
    const int f   = bid - 512;
    const int z   = f / 176;           // 0..15
    const int rem = f % 176;
    const int bx  = rem / 16;          // 0..10
    const int by  = rem & 15;          // 0..15
    const int e   = z & 7;
    const int R = HID, C = ISZ;
    const float* in = (z < 8 ? wg : wu) + (size_t)e * R * C;
    __bf16* out = (z < 8 ? wgT : wuT) + (size_t)e * R * C;
    const int rrA = by * 64, rrB = rrA;
    const int ccA = bx * 128, ccB = ccA + 64;
    const int lr  = tid >> 4;
    const int lc4 = (tid & 15) * 4;

    auto loadcvt = [&](int buf, int rr, int cc) {
        #pragma unroll
        for (int p = 0; p < 4; ++p) {
            float4 v = *(const float4*)(in + (size_t)(rr + p * 16 + lr) * C + cc + lc4);
            bf16x4 w;
            w[0] = (__bf16)v.x; w[1] = (__bf16)v.y; w[2] = (__bf16)v.z; w[3] = (__bf16)v.w;
            *(bf16x4*)&tb[buf][p * 16 + lr][lc4] = w;
        }
    };
    auto storeT = [&](int buf, int rr, int cc) {
        #pragma unroll
        for (int q = 0; q < 2; ++q) {
            const int oc = (tid >> 3) + 32 * q;
            const int vs = (tid & 7) * 8;
            bf16x8 w;
            #pragma unroll
            for (int j = 0; j < 8; ++j) w[j] = tb[buf][vs + j][oc];
            *(bf16x8*)(out + (size_t)(cc + oc) * R + rr + vs) = w;
        }
    };

    loadcvt(0, rrA, ccA);
    __syncthreads();
    loadcvt(1, rrB, ccB);
    storeT(0, rrA, ccA);
    __syncthreads();
    storeT(1, rrB, ccB);
}

// ---------------- Histogram + scan + assign + tile table (single block, 1024 thr) --------
__global__ __launch_bounds__(1024) void scan_assign_kernel(
    int* __restrict__ tiles,
    const int* __restrict__ sel, const float* __restrict__ wt,
    int* __restrict__ rtok, float* __restrict__ rwt, int* __restrict__ tok2row)
{
    __shared__ int hist[NEXP];
    __shared__ int soff[NEXP];
    __shared__ int scur[NEXP];
    if (threadIdx.x < NEXP) { hist[threadIdx.x] = 0; scur[threadIdx.x] = 0; }
    __syncthreads();
    for (int t = threadIdx.x; t < T_TOKENS; t += 1024) {
        atomicAdd(&hist[sel[t * 2 + 0]], 1);
        atomicAdd(&hist[sel[t * 2 + 1]], 1);
    }
    __syncthreads();
    if (threadIdx.x == 0) {
        int cur = 0, tix = 0;
        for (int e = 0; e < NEXP; ++e) {
            soff[e] = cur;
            int n64 = (hist[e] + 63) & ~63;            // 64-row tile alignment
            for (int rt = 0; rt * 64 < n64; ++rt)
                tiles[tix++] = (e << 16) | (cur + rt * 64);
            cur += n64;
        }
        for (; tix < TILES_MAX; ++tix) tiles[tix] = -1;
    }
    __syncthreads();
    for (int t = threadIdx.x; t < T_TOKENS; t += 1024) {
        #pragma unroll
        for (int k = 0; k < 2; ++k) {
            int e = sel[t * 2 + k];
            int pos = atomicAdd(&scur[e], 1);
            int row = soff[e] + pos;
            rtok[row] = t + 1;          // sentinel: 0 = pad row
            rwt[row] = wt[t * 2 + k];
            tok2row[t * 2 + k] = row;
        }
    }
}

// ---------------- FFN1 + deferred wd-cvt rider ----------------
// FFN1: BM=64, BN=64+64, BK=32, 32x32x16, 3-buf depth-2 counted-vmcnt (vmcnt(6)).
// LDS 36 KB -> 4 blocks/CU. Rider: wd transpose-convert (blocks 1584..2991).
__global__ __launch_bounds__(256) void ffn1_kernel(
    const __bf16* __restrict__ xb, const int* __restrict__ rtok,
    const __bf16* __restrict__ wgT, const __bf16* __restrict__ wuT,
    const int* __restrict__ tiles, __bf16* __restrict__ inter,
    const float* __restrict__ wd, __bf16* __restrict__ wdT)
{
    __shared__ __align__(16) char smem[36864];   // union: ffn1 36 KB | tcvt 17.9 KB
    const int n   = blockIdx.x;
    const int tid = threadIdx.x;

    if (n >= 22 * TILES_MAX) {
        // ---- wd-cvt rider: 1408 blocks x 2 tiles ----
        auto tb = (__bf16 (*)[64][70])smem;
        const int f   = n - 22 * TILES_MAX;
        const int e   = f / 176;
        const int rem = f % 176;
        const int bx  = rem / 16;          // 0..10
        const int by  = rem & 15;          // 0..15
        const int R = ISZ, C = HID;
        const float* in = wd + (size_t)e * R * C;
        __bf16* out = wdT + (size_t)e * R * C;
        const int ccA = by * 64, ccB = ccA;
        const int rrA = bx * 128, rrB = rrA + 64;
        const int lr  = tid >> 4;
        const int lc4 = (tid & 15) * 4;

        auto loadcvt = [&](int buf, int rr, int cc) {
            #pragma unroll
            for (int p = 0; p < 4; ++p) {
                float4 v = *(const float4*)(in + (size_t)(rr + p * 16 + lr) * C + cc + lc4);
                bf16x4 w;
                w[0] = (__bf16)v.x; w[1] = (__bf16)v.y; w[2] = (__bf16)v.z; w[3] = (__bf16)v.w;
                *(bf16x4*)&tb[buf][p * 16 + lr][lc4] = w;
            }
        };
        auto storeT = [&](int buf, int rr, int cc) {
            #pragma unroll
            for (int q = 0; q < 2; ++q) {
                const int oc = (tid >> 3) + 32 * q;
                const int vs = (tid & 7) * 8;
                bf16x8 w;
                #pragma unroll
                for (int j = 0; j < 8; ++j) w[j] = tb[buf][vs + j][oc];
                *(bf16x8*)(out + (size_t)(cc + oc) * R + rr + vs) = w;
            }
        };

        loadcvt(0, rrA, ccA);
        __syncthreads();
        loadcvt(1, rrB, ccB);
        storeT(0, rrA, ccA);
        __syncthreads();
        storeT(1, rrB, ccB);
        return;
    }

    // ---- FFN1 role (grid 1584 = 22 stripes x 72 tiles; XCD chunks of 198) ----
    auto sA = (__bf16 (*)[64][32])(smem);            // [3][64][32] = 12 KB
    auto sG = (__bf16 (*)[64][32])(smem + 12288);
    auto sU = (__bf16 (*)[64][32])(smem + 24576);

    const int nn = (n & 7) * 198 + (n >> 3);
    const int i0 = (nn / TILES_MAX) * 64;      // stripe 0..21
    const int tv = tiles[nn % TILES_MAX];
    if (tv < 0) return;
    const int e = tv >> 16;
    const int rowbase = tv & 0xFFFF;

    const int lane = tid & 63;
    const int wid  = tid >> 6;
    const int wr = wid >> 1, wc = wid & 1;
    const int l31 = lane & 31;
    const int kg  = lane >> 5;                 // k-half 0/1

    const int r16 = lane >> 2;
    const int cz  = (((lane & 3) ^ ((r16 >> 1) & 3)) * 8);
    const int rowA = rowbase + wid * 16 + r16;
    const int tokp = rtok[rowA];
    const int src  = tokp ? (tokp - 1) : T_TOKENS;     // pad rows -> zero row
    const __bf16* A0 = xb + (size_t)src * HID + cz;
    const size_t wb = (size_t)e * ISZ * HID + (size_t)(i0 + wid * 16 + r16) * HID + cz;
    const __bf16* G0 = wgT + wb;
    const __bf16* U0 = wuT + wb;

    f32x16 accG, accU;
    #pragma unroll
    for (int r = 0; r < 16; ++r) { accG[r] = 0.f; accU[r] = 0.f; }

    auto stage = [&](int b, int k0) {   // 3 gload16 per wave
        gload16(A0 + k0, &sA[b][wid * 16][0]);
        gload16(G0 + k0, &sG[b][wid * 16][0]);
        gload16(U0 + k0, &sU[b][wid * 16][0]);
    };
    auto compute = [&](int b) {
        #pragma unroll
        for (int s = 0; s < 2; ++s) {
            const int ch = ((2 * s + kg) ^ ((l31 >> 1) & 3)) * 8;
            bf16x8 a_ = *(const bf16x8*)&sA[b][wr * 32 + l31][ch];
            bf16x8 g_ = *(const bf16x8*)&sG[b][wc * 32 + l31][ch];
            bf16x8 u_ = *(const bf16x8*)&sU[b][wc * 32 + l31][ch];
            __builtin_amdgcn_s_setprio(1);
            accG = __builtin_amdgcn_mfma_f32_32x32x16_bf16(a_, g_, accG, 0, 0, 0);
            accU = __builtin_amdgcn_mfma_f32_32x32x16_bf16(a_, u_, accU, 0, 0, 0);
            __builtin_amdgcn_s_setprio(0);
        }
    };

    const int nIter = HID / 32;   // 32
    stage(0, 0);
    stage(1, 32);
    PIPE_BARRIER(3)               // stage0 landed; stage1 (3 loads) in flight
    for (int i = 0; i < nIter; ++i) {
        int ks = (i + 2 < nIter) ? (i + 2) * 32 : 0;   // clamped dead stage keeps counts uniform
        stage((i + 2) % 3, ks);
        compute(i % 3);
        PIPE_BARRIER(3)           // stage(i+1) landed; newest stage in flight
    }

    // epilogue: silu(G)*U -> bf16 inter (D: col = lane&31, row = (r&3)+8*(r>>2)+4*kg)
    const int base_row = rowbase + wr * 32;
    #pragma unroll
    for (int r = 0; r < 16; ++r) {
        float g = accG[r];
        float u = accU[r];
        float v = g / (1.0f + __expf(-g)) * u;
        int row = base_row + (r & 3) + 8 * (r >> 2) + 4 * kg;
        inter[(size_t)row * ISZ + i0 + wc * 32 + l31] = (__bf16)v;
    }
}

// ---------------- FFN2: y[row] = bf16(rwt[row] * (inter[row] @ WdT')) ----------------
// BM=64, BN=128, BK=32, 3-buf depth-2 counted-vmcnt (vmcnt(3)). 36 KB -> 4 blocks/CU.
__global__ __launch_bounds__(256) void ffn2_kernel(
    const __bf16* __restrict__ inter, const __bf16* __restrict__ wdT,
    const float* __restrict__ rwt, const int* __restrict__ tiles,
    __bf16* __restrict__ y)
{
    // grid 576 = 8 stripes x 72 tiles; XCD chunks of 72
    const int n  = blockIdx.x;
    const int nn = (n & 7) * 72 + (n >> 3);
    const int n0 = (nn / TILES_MAX) * 128;     // stripe 0..7
    const int tv = tiles[nn % TILES_MAX];
    if (tv < 0) return;
    const int e = tv >> 16;
    const int rowbase = tv & 0xFFFF;

    __shared__ __align__(16) __bf16 sA[3][64][32];   // 12 KB
    __shared__ __align__(16) __bf16 sB[3][128][32];  // 24 KB -> 36 KB

    const int lane = threadIdx.x & 63;
    const int wid  = threadIdx.x >> 6;
    const int wr = wid >> 1, wc = wid & 1;
    const int l31 = lane & 31;
    const int kg  = lane >> 5;

    const int r16 = lane >> 2;
    const int cz  = (((lane & 3) ^ ((r16 >> 1) & 3)) * 8);
    const __bf16* A0 = inter + (size_t)(rowbase + wid * 16 + r16) * ISZ + cz;
    const __bf16* B0 = wdT + (size_t)e * HID * ISZ + (size_t)(n0 + wid * 32 + r16) * ISZ + cz;
    const size_t rstepB = (size_t)16 * ISZ;

    f32x16 acc[2];
    #pragma unroll
    for (int q = 0; q < 2; ++q)
        #pragma unroll
        for (int r = 0; r < 16; ++r) acc[q][r] = 0.f;

    auto stage = [&](int b, int k0) {   // 3 gload16 per wave
        gload16(A0 + k0,          &sA[b][wid * 16][0]);
        gload16(B0 + k0,          &sB[b][wid * 32][0]);
        gload16(B0 + k0 + rstepB, &sB[b][wid * 32 + 16][0]);
    };
    auto compute = [&](int b) {
        #pragma unroll
        for (int s = 0; s < 2; ++s) {
            const int ch = ((2 * s + kg) ^ ((l31 >> 1) & 3)) * 8;
            bf16x8 a_ = *(const bf16x8*)&sA[b][wr * 32 + l31][ch];
            bf16x8 b0 = *(const bf16x8*)&sB[b][wc * 64 + l31][ch];
            bf16x8 b1 = *(const bf16x8*)&sB[b][wc * 64 + 32 + l31][ch];
            __builtin_amdgcn_s_setprio(1);
            acc[0] = __builtin_amdgcn_mfma_f32_32x32x16_bf16(a_, b0, acc[0], 0, 0, 0);
            acc[1] = __builtin_amdgcn_mfma_f32_32x32x16_bf16(a_, b1, acc[1], 0, 0, 0);
            __builtin_amdgcn_s_setprio(0);
        }
    };

    const int nIter = ISZ / 32;   // 44
    stage(0, 0);
    stage(1, 32);
    PIPE_BARRIER(3)
    for (int i = 0; i < nIter; ++i) {
        int ks = (i + 2 < nIter) ? (i + 2) * 32 : 0;
        stage((i + 2) % 3, ks);
        compute(i % 3);
        PIPE_BARRIER(3)
    }

    const int base_row = rowbase + wr * 32;
    #pragma unroll
    for (int q = 0; q < 2; ++q) {
        const int col = n0 + wc * 64 + q * 32 + l31;
        #pragma unroll
        for (int r = 0; r < 16; ++r) {
            int row = base_row + (r & 3) + 8 * (r >> 2) + 4 * kg;
            y[(size_t)row * HID + col] = (__bf16)(rwt[row] * acc[q][r]);
        }
    }
}

// ---------------- Combine: out[t] = y[row0(t)] + y[row1(t)]  (y is bf16) ----------------
__global__ __launch_bounds__(256) void combine_kernel(
    const __bf16* __restrict__ y, const int* __restrict__ tok2row, float* __restrict__ out)
{
    const int idx = blockIdx.x * 256 + threadIdx.x;   // over T_TOKENS * HID/8
    const int t = idx >> 7;            // HID/8 = 128 groups per token
    const int c = (idx & 127) * 8;
    const int r0 = tok2row[t * 2];
    const int r1 = tok2row[t * 2 + 1];
    bf16x8 a = *(const bf16x8*)(y + (size_t)r0 * HID + c);
    bf16x8 b = *(const bf16x8*)(y + (size_t)r1 * HID + c);
    float4 o0, o1;
    o0.x = (float)a[0] + (float)b[0]; o0.y = (float)a[1] + (float)b[1];
    o0.z = (float)a[2] + (float)b[2]; o0.w = (float)a[3] + (float)b[3];
    o1.x = (float)a[4] + (float)b[4]; o1.y = (float)a[5] + (float)b[5];
    o1.z = (float)a[6] + (float)b[6]; o1.w = (float)a[7] + (float)b[7];
    *(float4*)(out + (size_t)t * HID + c) = o0;
    *(float4*)(out + (size_t)t * HID + c + 4) = o1;
}

extern "C" void kernel_launch(void* const* d_in, const int* in_sizes, int n_in,
                              void* d_out, int out_size, void* d_ws, size_t ws_size,
                              hipStream_t stream) {
    const float* x  = (const float*)d_in[0];
    const float* gw = (const float*)d_in[1];
    const float* wg = (const float*)d_in[2];
    const float* wu = (const float*)d_in[3];
    const float* wd = (const float*)d_in[4];
    float* out = (float*)d_out;

    char* ws = (char*)d_ws;
    int*    tiles   = (int*)(ws + 64);           // 72 ints
    int*    sel     = (int*)(ws + 1024);         // 4096 ints
    float*  wtp     = (float*)(ws + 17408);      // 4096 f32
    int*    rtok    = (int*)(ws + 33792);        // 4608 ints
    float*  rwt     = (float*)(ws + 52224);      // 4608 f32
    int*    tok2row = (int*)(ws + 70656);        // 4096 ints -> ends 87040
    __bf16* xb      = (__bf16*)(ws + 87040);     // 2049*1024 bf16 = 4.20 MB
    __bf16* inter   = (__bf16*)(ws + 4283648);   // 4608*1408 bf16 = 12.98 MB
    __bf16* wgT     = (__bf16*)(ws + 17260032);  // 23.07 MB
    __bf16* wuT     = (__bf16*)(ws + 40328704);  // 23.07 MB
    __bf16* wdT     = (__bf16*)(ws + 63397376);  // 23.07 MB -> ends 86.5 MB
    __bf16* y       = (__bf16*)wgT;              // alias: wgT dead after ffn1 (9.4 MB)

    // zero: tiles + rtok (sentinel 0 = pad) + rwt + headers
    hipMemsetAsync(ws, 0, 87040, stream);

    prep_kernel<<<3328, 256, 0, stream>>>(x, gw, sel, wtp, xb, wg, wu, wgT, wuT);
    scan_assign_kernel<<<1, 1024, 0, stream>>>(tiles, sel, wtp, rtok, rwt, tok2row);

    // ffn1 (1584) + deferred wd-cvt rider (1408)
    ffn1_kernel<<<22 * TILES_MAX + 1408, 256, 0, stream>>>(
        xb, rtok, wgT, wuT, tiles, inter, wd, wdT);
    ffn2_kernel<<<8 * TILES_MAX, 256, 0, stream>>>(inter, wdT, rwt, tiles, y);          // 576
    combine_kernel<<<(T_TOKENS * HID / 8) / 256, 256, 0, stream>>>(y, tok2row, out);
}

// Round 26
// 132.869 us; speedup vs baseline: 1.1657x; 1.0079x over previous
//
#include <hip/hip_runtime.h>
#include <hip/hip_bf16.h>

#define T_TOKENS 2048
#define HID 1024
#define ISZ 1408
#define NEXP 8
#define TILES_MAX 72    // sum ceil(cnt_e/64) <= 4096/64 + 8 = 72

typedef __bf16 bf16x8 __attribute__((ext_vector_type(8)));
typedef __bf16 bf16x4 __attribute__((ext_vector_type(4)));
typedef float  f32x16 __attribute__((ext_vector_type(16)));

__device__ __forceinline__ void gload16(const void* g, void* l) {
    __builtin_amdgcn_global_load_lds(
        (const __attribute__((address_space(1))) void*)g,
        (__attribute__((address_space(3))) void*)l,
        16, 0, 0);
}

// counted-vmcnt barrier: newest N loads may stay in flight; everything older done.
#define PIPE_BARRIER(N)                                              \
    asm volatile("s_waitcnt vmcnt(" #N ") lgkmcnt(0)" ::: "memory"); \
    __builtin_amdgcn_sched_barrier(0);                               \
    __builtin_amdgcn_s_barrier();                                    \
    __builtin_amdgcn_sched_barrier(0);

// ---------------- prep: router (0..511) + wg/wu tcvt (512..3327) + wd tcvt e0-3 (3328..4031)
__global__ __launch_bounds__(256) void prep_kernel(
    const float* __restrict__ x, const float* __restrict__ gw,
    int* __restrict__ sel, float* __restrict__ wt, __bf16* __restrict__ xb,
    const float* __restrict__ wg, const float* __restrict__ wu, const float* __restrict__ wd,
    __bf16* __restrict__ wgT, __bf16* __restrict__ wuT, __bf16* __restrict__ wdT)
{
    __shared__ __bf16 tb[2][64][70];   // 17.9 KB (tcvt roles; router blocks leave it unused)
    const int bid = blockIdx.x;
    const int tid = threadIdx.x;

    if (bid < 512) {
        // ---- router role (R19-verified zero-LDS math) ----
        const int wave = tid >> 6;
        const int lane = tid & 63;
        const int t = bid * 4 + wave;
        const float* xr = x + (size_t)t * HID;

        const int c0 = lane * 16;
        float4 v0 = *(const float4*)(xr + c0);
        float4 v1 = *(const float4*)(xr + c0 + 4);
        float4 v2 = *(const float4*)(xr + c0 + 8);
        float4 v3 = *(const float4*)(xr + c0 + 12);
        {
            bf16x8 o0, o1;
            o0[0]=(__bf16)v0.x; o0[1]=(__bf16)v0.y; o0[2]=(__bf16)v0.z; o0[3]=(__bf16)v0.w;
            o0[4]=(__bf16)v1.x; o0[5]=(__bf16)v1.y; o0[6]=(__bf16)v1.z; o0[7]=(__bf16)v1.w;
            o1[0]=(__bf16)v2.x; o1[1]=(__bf16)v2.y; o1[2]=(__bf16)v2.z; o1[3]=(__bf16)v2.w;
            o1[4]=(__bf16)v3.x; o1[5]=(__bf16)v3.y; o1[6]=(__bf16)v3.z; o1[7]=(__bf16)v3.w;
            *(bf16x8*)(xb + (size_t)t * HID + c0) = o0;
            *(bf16x8*)(xb + (size_t)t * HID + c0 + 8) = o1;
        }
        if (bid == 0 && tid < 128) {   // zero pad-row
            bf16x8 z8;
            #pragma unroll
            for (int j = 0; j < 8; ++j) z8[j] = (__bf16)0.f;
            *(bf16x8*)(xb + (size_t)T_TOKENS * HID + tid * 8) = z8;
        }

        float le[8] = {0.f, 0.f, 0.f, 0.f, 0.f, 0.f, 0.f, 0.f};
        float xv[16];
        xv[0]=v0.x; xv[1]=v0.y; xv[2]=v0.z; xv[3]=v0.w;
        xv[4]=v1.x; xv[5]=v1.y; xv[6]=v1.z; xv[7]=v1.w;
        xv[8]=v2.x; xv[9]=v2.y; xv[10]=v2.z; xv[11]=v2.w;
        xv[12]=v3.x; xv[13]=v3.y; xv[14]=v3.z; xv[15]=v3.w;
        #pragma unroll
        for (int j = 0; j < 16; ++j) {
            const float* gr = gw + (size_t)(c0 + j) * NEXP;
            float4 g0 = *(const float4*)gr;
            float4 g1 = *(const float4*)(gr + 4);
            le[0] += xv[j] * g0.x; le[1] += xv[j] * g0.y;
            le[2] += xv[j] * g0.z; le[3] += xv[j] * g0.w;
            le[4] += xv[j] * g1.x; le[5] += xv[j] * g1.y;
            le[6] += xv[j] * g1.z; le[7] += xv[j] * g1.w;
        }
        #pragma unroll
        for (int d = 1; d < 64; d <<= 1) {
            #pragma unroll
            for (int k = 0; k < 8; ++k) le[k] += __shfl_xor(le[k], d);
        }
        float m = le[0];
        #pragma unroll
        for (int k = 1; k < 8; ++k) m = fmaxf(m, le[k]);
        float pe[8]; float s = 0.f;
        #pragma unroll
        for (int k = 0; k < 8; ++k) { pe[k] = expf(le[k] - m); s += pe[k]; }
        int e1 = 0; float p1 = pe[0];
        #pragma unroll
        for (int k = 1; k < 8; ++k) if (pe[k] > p1) { p1 = pe[k]; e1 = k; }
        int e2 = -1; float p2 = -1.f;
        #pragma unroll
        for (int k = 0; k < 8; ++k) if (k != e1 && pe[k] > p2) { p2 = pe[k]; e2 = k; }
        if (lane == 0) {
            float inv = 1.0f / (p1 + p2);
            sel[t * 2 + 0] = e1; sel[t * 2 + 1] = e2;
            wt[t * 2 + 0] = p1 * inv; wt[t * 2 + 1] = p2 * inv;
        }
        return;
    }

    const int lr  = tid >> 4;
    const int lc4 = (tid & 15) * 4;
    const float* in;
    __bf16* out;
    int R, C, rrA, ccA, rrB, ccB;

    if (bid < 3328) {
        // ---- wg/wu tcvt: 2816 blocks x 2 tiles ----
        const int f   = bid - 512;
        const int z   = f / 176;           // 0..15
        const int rem = f % 176;
        const int bx  = rem / 16;          // 0..10
        const int by  = rem & 15;          // 0..15
        const int e   = z & 7;
        R = HID; C = ISZ;
        in  = (z < 8 ? wg : wu) + (size_t)e * R * C;
        out = (z < 8 ? wgT : wuT) + (size_t)e * R * C;
        rrA = by * 64; rrB = rrA;
        ccA = bx * 128; ccB = ccA + 64;
    } else {
        // ---- wd tcvt, experts 0..3: 704 blocks x 2 tiles ----
        const int f   = bid - 3328;
        const int e   = f / 176;           // 0..3
        const int rem = f % 176;
        const int bx  = rem / 16;          // 0..10
        const int by  = rem & 15;          // 0..15
        R = ISZ; C = HID;
        in  = wd  + (size_t)e * R * C;
        out = wdT + (size_t)e * R * C;
        ccA = by * 64; ccB = ccA;
        rrA = bx * 128; rrB = rrA + 64;
    }

    auto loadcvt = [&](int buf, int rr, int cc) {
        #pragma unroll
        for (int p = 0; p < 4; ++p) {
            float4 v = *(const float4*)(in + (size_t)(rr + p * 16 + lr) * C + cc + lc4);
            bf16x4 w;
            w[0] = (__bf16)v.x; w[1] = (__bf16)v.y; w[2] = (__bf16)v.z; w[3] = (__bf16)v.w;
            *(bf16x4*)&tb[buf][p * 16 + lr][lc4] = w;
        }
    };
    auto storeT = [&](int buf, int rr, int cc) {
        #pragma unroll
        for (int q = 0; q < 2; ++q) {
            const int oc = (tid >> 3) + 32 * q;
            const int vs = (tid & 7) * 8;
            bf16x8 w;
            #pragma unroll
            for (int j = 0; j < 8; ++j) w[j] = tb[buf][vs + j][oc];
            *(bf16x8*)(out + (size_t)(cc + oc) * R + rr + vs) = w;
        }
    };

    loadcvt(0, rrA, ccA);
    __syncthreads();
    loadcvt(1, rrB, ccB);
    storeT(0, rrA, ccA);
    __syncthreads();
    storeT(1, rrB, ccB);
}

// ---------------- Histogram + scan + assign + tile table + pad-row zeroing ---------------
__global__ __launch_bounds__(1024) void scan_assign_kernel(
    int* __restrict__ tiles,
    const int* __restrict__ sel, const float* __restrict__ wt,
    int* __restrict__ rtok, float* __restrict__ rwt, int* __restrict__ tok2row)
{
    __shared__ int hist[NEXP];
    __shared__ int soff[NEXP];
    __shared__ int snal[NEXP];   // 64-aligned counts
    __shared__ int scur[NEXP];
    if (threadIdx.x < NEXP) { hist[threadIdx.x] = 0; scur[threadIdx.x] = 0; }
    __syncthreads();
    for (int t = threadIdx.x; t < T_TOKENS; t += 1024) {
        atomicAdd(&hist[sel[t * 2 + 0]], 1);
        atomicAdd(&hist[sel[t * 2 + 1]], 1);
    }
    __syncthreads();
    if (threadIdx.x == 0) {
        int cur = 0, tix = 0;
        for (int e = 0; e < NEXP; ++e) {
            soff[e] = cur;
            int n64 = (hist[e] + 63) & ~63;            // 64-row tile alignment
            snal[e] = n64;
            for (int rt = 0; rt * 64 < n64; ++rt)
                tiles[tix++] = (e << 16) | (cur + rt * 64);
            cur += n64;
        }
        for (; tix < TILES_MAX; ++tix) tiles[tix] = -1;
    }
    __syncthreads();
    // zero pad-row rtok entries (sentinel 0 = pad); replaces the host-side memset
    for (int e = 0; e < NEXP; ++e) {
        const int lo = soff[e] + hist[e], hi = soff[e] + snal[e];
        for (int r = lo + (int)threadIdx.x; r < hi; r += 1024) rtok[r] = 0;
    }
    __syncthreads();
    for (int t = threadIdx.x; t < T_TOKENS; t += 1024) {
        #pragma unroll
        for (int k = 0; k < 2; ++k) {
            int e = sel[t * 2 + k];
            int pos = atomicAdd(&scur[e], 1);
            int row = soff[e] + pos;
            rtok[row] = t + 1;          // sentinel: 0 = pad row
            rwt[row] = wt[t * 2 + k];
            tok2row[t * 2 + k] = row;
        }
    }
}

// ---------------- FFN1 + deferred wd-cvt rider (experts 4..7) ----------------
// FFN1: BM=64, BN=64+64, BK=32, 32x32x16, 3-buf depth-2 counted-vmcnt (vmcnt(3)).
// LDS 36 KB -> 4 blocks/CU. Rider: wd transpose-convert e4-7 (blocks 1584..2287).
__global__ __launch_bounds__(256) void ffn1_kernel(
    const __bf16* __restrict__ xb, const int* __restrict__ rtok,
    const __bf16* __restrict__ wgT, const __bf16* __restrict__ wuT,
    const int* __restrict__ tiles, __bf16* __restrict__ inter,
    const float* __restrict__ wd, __bf16* __restrict__ wdT)
{
    __shared__ __align__(16) char smem[36864];   // union: ffn1 36 KB | tcvt 17.9 KB
    const int n   = blockIdx.x;
    const int tid = threadIdx.x;

    if (n >= 22 * TILES_MAX) {
        // ---- wd-cvt rider: 704 blocks x 2 tiles (experts 4..7) ----
        auto tb = (__bf16 (*)[64][70])smem;
        const int f   = n - 22 * TILES_MAX;
        const int e   = 4 + f / 176;
        const int rem = f % 176;
        const int bx  = rem / 16;          // 0..10
        const int by  = rem & 15;          // 0..15
        const int R = ISZ, C = HID;
        const float* in = wd + (size_t)e * R * C;
        __bf16* out = wdT + (size_t)e * R * C;
        const int ccA = by * 64, ccB = ccA;
        const int rrA = bx * 128, rrB = rrA + 64;
        const int lr  = tid >> 4;
        const int lc4 = (tid & 15) * 4;

        auto loadcvt = [&](int buf, int rr, int cc) {
            #pragma unroll
            for (int p = 0; p < 4; ++p) {
                float4 v = *(const float4*)(in + (size_t)(rr + p * 16 + lr) * C + cc + lc4);
                bf16x4 w;
                w[0] = (__bf16)v.x; w[1] = (__bf16)v.y; w[2] = (__bf16)v.z; w[3] = (__bf16)v.w;
                *(bf16x4*)&tb[buf][p * 16 + lr][lc4] = w;
            }
        };
        auto storeT = [&](int buf, int rr, int cc) {
            #pragma unroll
            for (int q = 0; q < 2; ++q) {
                const int oc = (tid >> 3) + 32 * q;
                const int vs = (tid & 7) * 8;
                bf16x8 w;
                #pragma unroll
                for (int j = 0; j < 8; ++j) w[j] = tb[buf][vs + j][oc];
                *(bf16x8*)(out + (size_t)(cc + oc) * R + rr + vs) = w;
            }
        };

        loadcvt(0, rrA, ccA);
        __syncthreads();
        loadcvt(1, rrB, ccB);
        storeT(0, rrA, ccA);
        __syncthreads();
        storeT(1, rrB, ccB);
        return;
    }

    // ---- FFN1 role (grid 1584 = 22 stripes x 72 tiles; XCD chunks of 198) ----
    auto sA = (__bf16 (*)[64][32])(smem);            // [3][64][32] = 12 KB
    auto sG = (__bf16 (*)[64][32])(smem + 12288);
    auto sU = (__bf16 (*)[64][32])(smem + 24576);

    const int nn = (n & 7) * 198 + (n >> 3);
    const int i0 = (nn / TILES_MAX) * 64;      // stripe 0..21
    const int tv = tiles[nn % TILES_MAX];
    if (tv < 0) return;
    const int e = tv >> 16;
    const int rowbase = tv & 0xFFFF;

    const int lane = tid & 63;
    const int wid  = tid >> 6;
    const int wr = wid >> 1, wc = wid & 1;
    const int l31 = lane & 31;
    const int kg  = lane >> 5;                 // k-half 0/1

    const int r16 = lane >> 2;
    const int cz  = (((lane & 3) ^ ((r16 >> 1) & 3)) * 8);
    const int rowA = rowbase + wid * 16 + r16;
    const int tokp = rtok[rowA];
    const int src  = tokp ? (tokp - 1) : T_TOKENS;     // pad rows -> zero row
    const __bf16* A0 = xb + (size_t)src * HID + cz;
    const size_t wb = (size_t)e * ISZ * HID + (size_t)(i0 + wid * 16 + r16) * HID + cz;
    const __bf16* G0 = wgT + wb;
    const __bf16* U0 = wuT + wb;

    f32x16 accG, accU;
    #pragma unroll
    for (int r = 0; r < 16; ++r) { accG[r] = 0.f; accU[r] = 0.f; }

    auto stage = [&](int b, int k0) {   // 3 gload16 per wave
        gload16(A0 + k0, &sA[b][wid * 16][0]);
        gload16(G0 + k0, &sG[b][wid * 16][0]);
        gload16(U0 + k0, &sU[b][wid * 16][0]);
    };
    auto compute = [&](int b) {
        #pragma unroll
        for (int s = 0; s < 2; ++s) {
            const int ch = ((2 * s + kg) ^ ((l31 >> 1) & 3)) * 8;
            bf16x8 a_ = *(const bf16x8*)&sA[b][wr * 32 + l31][ch];
            bf16x8 g_ = *(const bf16x8*)&sG[b][wc * 32 + l31][ch];
            bf16x8 u_ = *(const bf16x8*)&sU[b][wc * 32 + l31][ch];
            __builtin_amdgcn_s_setprio(1);
            accG = __builtin_amdgcn_mfma_f32_32x32x16_bf16(a_, g_, accG, 0, 0, 0);
            accU = __builtin_amdgcn_mfma_f32_32x32x16_bf16(a_, u_, accU, 0, 0, 0);
            __builtin_amdgcn_s_setprio(0);
        }
    };

    const int nIter = HID / 32;   // 32
    stage(0, 0);
    stage(1, 32);
    PIPE_BARRIER(3)               // stage0 landed; stage1 (3 loads) in flight
    for (int i = 0; i < nIter; ++i) {
        int ks = (i + 2 < nIter) ? (i + 2) * 32 : 0;   // clamped dead stage keeps counts uniform
        stage((i + 2) % 3, ks);
        compute(i % 3);
        PIPE_BARRIER(3)           // stage(i+1) landed; newest stage in flight
    }

    // epilogue: silu(G)*U -> bf16 inter (D: col = lane&31, row = (r&3)+8*(r>>2)+4*kg)
    const int base_row = rowbase + wr * 32;
    #pragma unroll
    for (int r = 0; r < 16; ++r) {
        float g = accG[r];
        float u = accU[r];
        float v = g / (1.0f + __expf(-g)) * u;
        int row = base_row + (r & 3) + 8 * (r >> 2) + 4 * kg;
        inter[(size_t)row * ISZ + i0 + wc * 32 + l31] = (__bf16)v;
    }
}

// ---------------- FFN2: y[row] = bf16(rwt[row] * (inter[row] @ WdT')) ----------------
// BM=64, BN=128, BK=32, 3-buf depth-2 counted-vmcnt (vmcnt(3)). 36 KB -> 4 blocks/CU.
__global__ __launch_bounds__(256) void ffn2_kernel(
    const __bf16* __restrict__ inter, const __bf16* __restrict__ wdT,
    const float* __restrict__ rwt, const int* __restrict__ tiles,
    __bf16* __restrict__ y)
{
    // grid 576 = 8 stripes x 72 tiles; XCD chunks of 72
    const int n  = blockIdx.x;
    const int nn = (n & 7) * 72 + (n >> 3);
    const int n0 = (nn / TILES_MAX) * 128;     // stripe 0..7
    const int tv = tiles[nn % TILES_MAX];
    if (tv < 0) return;
    const int e = tv >> 16;
    const int rowbase = tv & 0xFFFF;

    __shared__ __align__(16) __bf16 sA[3][64][32];   // 12 KB
    __shared__ __align__(16) __bf16 sB[3][128][32];  // 24 KB -> 36 KB

    const int lane = threadIdx.x & 63;
    const int wid  = threadIdx.x >> 6;
    const int wr = wid >> 1, wc = wid & 1;
    const int l31 = lane & 31;
    const int kg  = lane >> 5;

    const int r16 = lane >> 2;
    const int cz  = (((lane & 3) ^ ((r16 >> 1) & 3)) * 8);
    const __bf16* A0 = inter + (size_t)(rowbase + wid * 16 + r16) * ISZ + cz;
    const __bf16* B0 = wdT + (size_t)e * HID * ISZ + (size_t)(n0 + wid * 32 + r16) * ISZ + cz;
    const size_t rstepB = (size_t)16 * ISZ;

    f32x16 acc[2];
    #pragma unroll
    for (int q = 0; q < 2; ++q)
        #pragma unroll
        for (int r = 0; r < 16; ++r) acc[q][r] = 0.f;

    auto stage = [&](int b, int k0) {   // 3 gload16 per wave
        gload16(A0 + k0,          &sA[b][wid * 16][0]);
        gload16(B0 + k0,          &sB[b][wid * 32][0]);
        gload16(B0 + k0 + rstepB, &sB[b][wid * 32 + 16][0]);
    };
    auto compute = [&](int b) {
        #pragma unroll
        for (int s = 0; s < 2; ++s) {
            const int ch = ((2 * s + kg) ^ ((l31 >> 1) & 3)) * 8;
            bf16x8 a_ = *(const bf16x8*)&sA[b][wr * 32 + l31][ch];
            bf16x8 b0 = *(const bf16x8*)&sB[b][wc * 64 + l31][ch];
            bf16x8 b1 = *(const bf16x8*)&sB[b][wc * 64 + 32 + l31][ch];
            __builtin_amdgcn_s_setprio(1);
            acc[0] = __builtin_amdgcn_mfma_f32_32x32x16_bf16(a_, b0, acc[0], 0, 0, 0);
            acc[1] = __builtin_amdgcn_mfma_f32_32x32x16_bf16(a_, b1, acc[1], 0, 0, 0);
            __builtin_amdgcn_s_setprio(0);
        }
    };

    const int nIter = ISZ / 32;   // 44
    stage(0, 0);
    stage(1, 32);
    PIPE_BARRIER(3)
    for (int i = 0; i < nIter; ++i) {
        int ks = (i + 2 < nIter) ? (i + 2) * 32 : 0;
        stage((i + 2) % 3, ks);
        compute(i % 3);
        PIPE_BARRIER(3)
    }

    const int base_row = rowbase + wr * 32;
    #pragma unroll
    for (int q = 0; q < 2; ++q) {
        const int col = n0 + wc * 64 + q * 32 + l31;
        #pragma unroll
        for (int r = 0; r < 16; ++r) {
            int row = base_row + (r & 3) + 8 * (r >> 2) + 4 * kg;
            y[(size_t)row * HID + col] = (__bf16)(rwt[row] * acc[q][r]);
        }
    }
}

// ---------------- Combine: out[t] = y[row0(t)] + y[row1(t)]  (y is bf16) ----------------
__global__ __launch_bounds__(256) void combine_kernel(
    const __bf16* __restrict__ y, const int* __restrict__ tok2row, float* __restrict__ out)
{
    const int idx = blockIdx.x * 256 + threadIdx.x;   // over T_TOKENS * HID/8
    const int t = idx >> 7;            // HID/8 = 128 groups per token
    const int c = (idx & 127) * 8;
    const int r0 = tok2row[t * 2];
    const int r1 = tok2row[t * 2 + 1];
    bf16x8 a = *(const bf16x8*)(y + (size_t)r0 * HID + c);
    bf16x8 b = *(const bf16x8*)(y + (size_t)r1 * HID + c);
    float4 o0, o1;
    o0.x = (float)a[0] + (float)b[0]; o0.y = (float)a[1] + (float)b[1];
    o0.z = (float)a[2] + (float)b[2]; o0.w = (float)a[3] + (float)b[3];
    o1.x = (float)a[4] + (float)b[4]; o1.y = (float)a[5] + (float)b[5];
    o1.z = (float)a[6] + (float)b[6]; o1.w = (float)a[7] + (float)b[7];
    *(float4*)(out + (size_t)t * HID + c) = o0;
    *(float4*)(out + (size_t)t * HID + c + 4) = o1;
}

extern "C" void kernel_launch(void* const* d_in, const int* in_sizes, int n_in,
                              void* d_out, int out_size, void* d_ws, size_t ws_size,
                              hipStream_t stream) {
    const float* x  = (const float*)d_in[0];
    const float* gw = (const float*)d_in[1];
    const float* wg = (const float*)d_in[2];
    const float* wu = (const float*)d_in[3];
    const float* wd = (const float*)d_in[4];
    float* out = (float*)d_out;

    char* ws = (char*)d_ws;
    int*    tiles   = (int*)(ws + 64);           // 72 ints
    int*    sel     = (int*)(ws + 1024);         // 4096 ints
    float*  wtp     = (float*)(ws + 17408);      // 4096 f32
    int*    rtok    = (int*)(ws + 33792);        // 4608 ints
    float*  rwt     = (float*)(ws + 52224);      // 4608 f32
    int*    tok2row = (int*)(ws + 70656);        // 4096 ints -> ends 87040
    __bf16* xb      = (__bf16*)(ws + 87040);     // 2049*1024 bf16 = 4.20 MB
    __bf16* inter   = (__bf16*)(ws + 4283648);   // 4608*1408 bf16 = 12.98 MB
    __bf16* wgT     = (__bf16*)(ws + 17260032);  // 23.07 MB
    __bf16* wuT     = (__bf16*)(ws + 40328704);  // 23.07 MB
    __bf16* wdT     = (__bf16*)(ws + 63397376);  // 23.07 MB -> ends 86.5 MB
    __bf16* y       = (__bf16*)wgT;              // alias: wgT dead after ffn1 (9.4 MB)

    // no memset: tiles/sel/wtp/tok2row fully written each call; pad rtok zeroed in scan_assign

    prep_kernel<<<4032, 256, 0, stream>>>(x, gw, sel, wtp, xb, wg, wu, wd, wgT, wuT, wdT);
    scan_assign_kernel<<<1, 1024, 0, stream>>>(tiles, sel, wtp, rtok, rwt, tok2row);

    // ffn1 (1584) + deferred wd-cvt rider e4-7 (704)
    ffn1_kernel<<<22 * TILES_MAX + 704, 256, 0, stream>>>(
        xb, rtok, wgT, wuT, tiles, inter, wd, wdT);
    ffn2_kernel<<<8 * TILES_MAX, 256, 0, stream>>>(inter, wdT, rwt, tiles, y);          // 576
    combine_kernel<<<(T_TOKENS * HID / 8) / 256, 256, 0, stream>>>(y, tok2row, out);
}

// Round 27
// 130.595 us; speedup vs baseline: 1.1860x; 1.0174x over previous
//
#include <hip/hip_runtime.h>
#include <hip/hip_bf16.h>

#define T_TOKENS 2048
#define HID 1024
#define ISZ 1408
#define NEXP 8
#define T128_MAX 40     // sum ceil(cnt_e/128) <= 4096/128 + 8 = 40
#define T64_MAX 80      // sum (n128_e/64) <= 5112/64 -> 80

typedef __bf16 bf16x8 __attribute__((ext_vector_type(8)));
typedef __bf16 bf16x4 __attribute__((ext_vector_type(4)));
typedef float  f32x16 __attribute__((ext_vector_type(16)));

__device__ __forceinline__ void gload16(const void* g, void* l) {
    __builtin_amdgcn_global_load_lds(
        (const __attribute__((address_space(1))) void*)g,
        (__attribute__((address_space(3))) void*)l,
        16, 0, 0);
}

// counted-vmcnt barrier: newest N loads may stay in flight; everything older done.
#define PIPE_BARRIER(N)                                              \
    asm volatile("s_waitcnt vmcnt(" #N ") lgkmcnt(0)" ::: "memory"); \
    __builtin_amdgcn_sched_barrier(0);                               \
    __builtin_amdgcn_s_barrier();                                    \
    __builtin_amdgcn_sched_barrier(0);

// ---------------- prep: router (0..511) + wg/wu tcvt (512..3327) + wd tcvt e0-3 (3328..4031)
__global__ __launch_bounds__(256) void prep_kernel(
    const float* __restrict__ x, const float* __restrict__ gw,
    int* __restrict__ sel, float* __restrict__ wt, __bf16* __restrict__ xb,
    const float* __restrict__ wg, const float* __restrict__ wu, const float* __restrict__ wd,
    __bf16* __restrict__ wgT, __bf16* __restrict__ wuT, __bf16* __restrict__ wdT)
{
    __shared__ __bf16 tb[2][64][70];   // 17.9 KB
    const int bid = blockIdx.x;
    const int tid = threadIdx.x;

    if (bid < 512) {
        // ---- router role (zero-LDS) ----
        const int wave = tid >> 6;
        const int lane = tid & 63;
        const int t = bid * 4 + wave;
        const float* xr = x + (size_t)t * HID;

        const int c0 = lane * 16;
        float4 v0 = *(const float4*)(xr + c0);
        float4 v1 = *(const float4*)(xr + c0 + 4);
        float4 v2 = *(const float4*)(xr + c0 + 8);
        float4 v3 = *(const float4*)(xr + c0 + 12);
        {
            bf16x8 o0, o1;
            o0[0]=(__bf16)v0.x; o0[1]=(__bf16)v0.y; o0[2]=(__bf16)v0.z; o0[3]=(__bf16)v0.w;
            o0[4]=(__bf16)v1.x; o0[5]=(__bf16)v1.y; o0[6]=(__bf16)v1.z; o0[7]=(__bf16)v1.w;
            o1[0]=(__bf16)v2.x; o1[1]=(__bf16)v2.y; o1[2]=(__bf16)v2.z; o1[3]=(__bf16)v2.w;
            o1[4]=(__bf16)v3.x; o1[5]=(__bf16)v3.y; o1[6]=(__bf16)v3.z; o1[7]=(__bf16)v3.w;
            *(bf16x8*)(xb + (size_t)t * HID + c0) = o0;
            *(bf16x8*)(xb + (size_t)t * HID + c0 + 8) = o1;
        }
        if (bid == 0 && tid < 128) {   // zero pad-row
            bf16x8 z8;
            #pragma unroll
            for (int j = 0; j < 8; ++j) z8[j] = (__bf16)0.f;
            *(bf16x8*)(xb + (size_t)T_TOKENS * HID + tid * 8) = z8;
        }

        float le[8] = {0.f, 0.f, 0.f, 0.f, 0.f, 0.f, 0.f, 0.f};
        float xv[16];
        xv[0]=v0.x; xv[1]=v0.y; xv[2]=v0.z; xv[3]=v0.w;
        xv[4]=v1.x; xv[5]=v1.y; xv[6]=v1.z; xv[7]=v1.w;
        xv[8]=v2.x; xv[9]=v2.y; xv[10]=v2.z; xv[11]=v2.w;
        xv[12]=v3.x; xv[13]=v3.y; xv[14]=v3.z; xv[15]=v3.w;
        #pragma unroll
        for (int j = 0; j < 16; ++j) {
            const float* gr = gw + (size_t)(c0 + j) * NEXP;
            float4 g0 = *(const float4*)gr;
            float4 g1 = *(const float4*)(gr + 4);
            le[0] += xv[j] * g0.x; le[1] += xv[j] * g0.y;
            le[2] += xv[j] * g0.z; le[3] += xv[j] * g0.w;
            le[4] += xv[j] * g1.x; le[5] += xv[j] * g1.y;
            le[6] += xv[j] * g1.z; le[7] += xv[j] * g1.w;
        }
        #pragma unroll
        for (int d = 1; d < 64; d <<= 1) {
            #pragma unroll
            for (int k = 0; k < 8; ++k) le[k] += __shfl_xor(le[k], d);
        }
        float m = le[0];
        #pragma unroll
        for (int k = 1; k < 8; ++k) m = fmaxf(m, le[k]);
        float pe[8]; float s = 0.f;
        #pragma unroll
        for (int k = 0; k < 8; ++k) { pe[k] = expf(le[k] - m); s += pe[k]; }
        int e1 = 0; float p1 = pe[0];
        #pragma unroll
        for (int k = 1; k < 8; ++k) if (pe[k] > p1) { p1 = pe[k]; e1 = k; }
        int e2 = -1; float p2 = -1.f;
        #pragma unroll
        for (int k = 0; k < 8; ++k) if (k != e1 && pe[k] > p2) { p2 = pe[k]; e2 = k; }
        if (lane == 0) {
            float inv = 1.0f / (p1 + p2);
            sel[t * 2 + 0] = e1; sel[t * 2 + 1] = e2;
            wt[t * 2 + 0] = p1 * inv; wt[t * 2 + 1] = p2 * inv;
        }
        return;
    }

    const int lr  = tid >> 4;
    const int lc4 = (tid & 15) * 4;
    const float* in;
    __bf16* out;
    int R, C, rrA, ccA, rrB, ccB;

    if (bid < 3328) {
        const int f   = bid - 512;
        const int z   = f / 176;           // 0..15
        const int rem = f % 176;
        const int bx  = rem / 16;          // 0..10
        const int by  = rem & 15;          // 0..15
        const int e   = z & 7;
        R = HID; C = ISZ;
        in  = (z < 8 ? wg : wu) + (size_t)e * R * C;
        out = (z < 8 ? wgT : wuT) + (size_t)e * R * C;
        rrA = by * 64; rrB = rrA;
        ccA = bx * 128; ccB = ccA + 64;
    } else {
        const int f   = bid - 3328;
        const int e   = f / 176;           // 0..3
        const int rem = f % 176;
        const int bx  = rem / 16;
        const int by  = rem & 15;
        R = ISZ; C = HID;
        in  = wd  + (size_t)e * R * C;
        out = wdT + (size_t)e * R * C;
        ccA = by * 64; ccB = ccA;
        rrA = bx * 128; rrB = rrA + 64;
    }

    auto loadcvt = [&](int buf, int rr, int cc) {
        #pragma unroll
        for (int p = 0; p < 4; ++p) {
            float4 v = *(const float4*)(in + (size_t)(rr + p * 16 + lr) * C + cc + lc4);
            bf16x4 w;
            w[0] = (__bf16)v.x; w[1] = (__bf16)v.y; w[2] = (__bf16)v.z; w[3] = (__bf16)v.w;
            *(bf16x4*)&tb[buf][p * 16 + lr][lc4] = w;
        }
    };
    auto storeT = [&](int buf, int rr, int cc) {
        #pragma unroll
        for (int q = 0; q < 2; ++q) {
            const int oc = (tid >> 3) + 32 * q;
            const int vs = (tid & 7) * 8;
            bf16x8 w;
            #pragma unroll
            for (int j = 0; j < 8; ++j) w[j] = tb[buf][vs + j][oc];
            *(bf16x8*)(out + (size_t)(cc + oc) * R + rr + vs) = w;
        }
    };

    loadcvt(0, rrA, ccA);
    __syncthreads();
    loadcvt(1, rrB, ccB);
    storeT(0, rrA, ccA);
    __syncthreads();
    storeT(1, rrB, ccB);
}

// ---------------- Histogram + scan + assign + dual tile tables + pad zeroing -------------
__global__ __launch_bounds__(1024) void scan_assign_kernel(
    int* __restrict__ tiles128, int* __restrict__ tiles64,
    const int* __restrict__ sel, const float* __restrict__ wt,
    int* __restrict__ rtok, float* __restrict__ rwt, int* __restrict__ tok2row)
{
    __shared__ int hist[NEXP];
    __shared__ int soff[NEXP];
    __shared__ int snal[NEXP];   // 128-aligned counts
    __shared__ int scur[NEXP];
    if (threadIdx.x < NEXP) { hist[threadIdx.x] = 0; scur[threadIdx.x] = 0; }
    __syncthreads();
    for (int t = threadIdx.x; t < T_TOKENS; t += 1024) {
        atomicAdd(&hist[sel[t * 2 + 0]], 1);
        atomicAdd(&hist[sel[t * 2 + 1]], 1);
    }
    __syncthreads();
    if (threadIdx.x == 0) {
        int cur = 0, t128 = 0, t64 = 0;
        for (int e = 0; e < NEXP; ++e) {
            soff[e] = cur;
            int n128 = (hist[e] + 127) & ~127;         // 128-row segment alignment
            snal[e] = n128;
            for (int rt = 0; rt * 128 < n128; ++rt)
                tiles128[t128++] = (e << 16) | (cur + rt * 128);
            for (int rt = 0; rt * 64 < n128; ++rt)
                tiles64[t64++] = (e << 16) | (cur + rt * 64);
            cur += n128;
        }
        for (; t128 < T128_MAX; ++t128) tiles128[t128] = -1;
        for (; t64 < T64_MAX; ++t64) tiles64[t64] = -1;
    }
    __syncthreads();
    // zero pad-row rtok entries (sentinel 0 = pad)
    for (int e = 0; e < NEXP; ++e) {
        const int lo = soff[e] + hist[e], hi = soff[e] + snal[e];
        for (int r = lo + (int)threadIdx.x; r < hi; r += 1024) rtok[r] = 0;
    }
    __syncthreads();
    for (int t = threadIdx.x; t < T_TOKENS; t += 1024) {
        #pragma unroll
        for (int k = 0; k < 2; ++k) {
            int e = sel[t * 2 + k];
            int pos = atomicAdd(&scur[e], 1);
            int row = soff[e] + pos;
            rtok[row] = t + 1;          // sentinel: 0 = pad row
            rwt[row] = wt[t * 2 + k];
            tok2row[t * 2 + k] = row;
        }
    }
}

// ---------------- FFN1 (8-wave, BM=128) + wd-cvt rider e4-7 ----------------
// FFN1: BM=128, BN=64(G)+64(U), BK=32, 32x32x16. Wave (wr 0-3, wc 0-1) owns 32r x 32c of
// BOTH G and U. 3-buf depth-2 counted-vmcnt, 2 gloads/wave/stage -> vmcnt(2).
// LDS 48 KB -> 3 blocks/CU = 24 waves/CU. Rider: blocks 880..1583, 512 threads.
__global__ __launch_bounds__(512) void ffn1_kernel(
    const __bf16* __restrict__ xb, const int* __restrict__ rtok,
    const __bf16* __restrict__ wgT, const __bf16* __restrict__ wuT,
    const int* __restrict__ tiles128, __bf16* __restrict__ inter,
    const float* __restrict__ wd, __bf16* __restrict__ wdT)
{
    __shared__ __align__(16) char smem[49152];   // union: ffn1 48 KB | tcvt 17.9 KB
    const int n   = blockIdx.x;
    const int tid = threadIdx.x;

    if (n >= 22 * T128_MAX) {
        // ---- wd-cvt rider: 704 blocks x 2 tiles (experts 4..7), 512 threads ----
        auto tb = (__bf16 (*)[64][70])smem;
        const int f   = n - 22 * T128_MAX;
        const int e   = 4 + f / 176;
        const int rem = f % 176;
        const int bx  = rem / 16;          // 0..10
        const int by  = rem & 15;          // 0..15
        const int R = ISZ, C = HID;
        const float* in = wd + (size_t)e * R * C;
        __bf16* out = wdT + (size_t)e * R * C;
        const int ccA = by * 64, ccB = ccA;
        const int rrA = bx * 128, rrB = rrA + 64;
        const int lr  = tid >> 4;          // 0..31
        const int lc4 = (tid & 15) * 4;

        auto loadcvt = [&](int buf, int rr, int cc) {
            #pragma unroll
            for (int p = 0; p < 2; ++p) {
                float4 v = *(const float4*)(in + (size_t)(rr + p * 32 + lr) * C + cc + lc4);
                bf16x4 w;
                w[0] = (__bf16)v.x; w[1] = (__bf16)v.y; w[2] = (__bf16)v.z; w[3] = (__bf16)v.w;
                *(bf16x4*)&tb[buf][p * 32 + lr][lc4] = w;
            }
        };
        auto storeT = [&](int buf, int rr, int cc) {
            #pragma unroll
            for (int q = 0; q < 2; ++q) {
                const int idx = q * 512 + tid;
                const int oc = idx >> 4;           // 0..63
                const int vs = (idx & 15) * 8;     // 0..120... (16 groups x 8 = 128? no: 64 cols)
                // tile is 64 wide: vs in 0..56 via (idx & 7) * 8; oc = idx >> 3 over 0..127?
                // 64 out-rows x 8 groups = 512 stores per tile-half; use 8 groups of 8:
                (void)oc; (void)vs;
            }
            // correct mapping: 64 out-rows x 8 bf16x8-groups = 512 = one store per thread
            const int oc = tid >> 3;               // 0..63
            const int vs = (tid & 7) * 8;          // 0..56
            bf16x8 w;
            #pragma unroll
            for (int j = 0; j < 8; ++j) w[j] = tb[buf][vs + j][oc];
            *(bf16x8*)(out + (size_t)(cc + oc) * R + rr + vs) = w;
        };

        loadcvt(0, rrA, ccA);
        __syncthreads();
        loadcvt(1, rrB, ccB);
        storeT(0, rrA, ccA);
        __syncthreads();
        storeT(1, rrB, ccB);
        return;
    }

    // ---- FFN1 role (grid 880 = 22 stripes x 40 tiles; XCD chunks of 110) ----
    auto sA = (__bf16 (*)[128][32])(smem);           // [3][128][32] = 24 KB
    auto sG = (__bf16 (*)[64][32])(smem + 24576);    // [3][64][32]  = 12 KB
    auto sU = (__bf16 (*)[64][32])(smem + 36864);    // [3][64][32]  = 12 KB

    const int nn = (n & 7) * 110 + (n >> 3);
    const int i0 = (nn / T128_MAX) * 64;       // stripe 0..21
    const int tv = tiles128[nn % T128_MAX];
    if (tv < 0) return;
    const int e = tv >> 16;
    const int rowbase = tv & 0xFFFF;

    const int lane = tid & 63;
    const int wid  = tid >> 6;                 // 0..7
    const int wr = wid >> 1, wc = wid & 1;     // wr 0..3, wc 0..1
    const int l31 = lane & 31;
    const int kg  = lane >> 5;                 // k-half 0/1

    // staging: gload16 covers 16 rows x 64B; lane: row = lane>>2, slot = lane&3.
    // slot s at row R holds global chunk s ^ ((R>>1)&3)  (involution; bases == 0 mod 16).
    const int r16 = lane >> 2;
    const int cz  = (((lane & 3) ^ ((r16 >> 1) & 3)) * 8);
    const int rowA = rowbase + wid * 16 + r16;         // 128 rows over 8 waves
    const int tokp = rtok[rowA];
    const int src  = tokp ? (tokp - 1) : T_TOKENS;     // pad rows -> zero row
    const __bf16* A0 = xb + (size_t)src * HID + cz;
    // weight staging: waves 0-3 stage G rows wid*16; waves 4-7 stage U rows (wid-4)*16
    const int wrow = (wid & 3) * 16 + r16;
    const __bf16* W0 = (wid < 4 ? wgT : wuT)
                     + (size_t)e * ISZ * HID + (size_t)(i0 + wrow) * HID + cz;

    f32x16 accG, accU;
    #pragma unroll
    for (int r = 0; r < 16; ++r) { accG[r] = 0.f; accU[r] = 0.f; }

    auto stage = [&](int b, int k0) {   // 2 gloads per wave
        gload16(A0 + k0, &sA[b][wid * 16][0]);
        if (wid < 4) gload16(W0 + k0, &sG[b][(wid & 3) * 16][0]);
        else         gload16(W0 + k0, &sU[b][(wid & 3) * 16][0]);
    };
    auto compute = [&](int b) {
        #pragma unroll
        for (int s = 0; s < 2; ++s) {
            const int ch = ((2 * s + kg) ^ ((l31 >> 1) & 3)) * 8;
            bf16x8 a_ = *(const bf16x8*)&sA[b][wr * 32 + l31][ch];
            bf16x8 g_ = *(const bf16x8*)&sG[b][wc * 32 + l31][ch];
            bf16x8 u_ = *(const bf16x8*)&sU[b][wc * 32 + l31][ch];
            __builtin_amdgcn_s_setprio(1);
            accG = __builtin_amdgcn_mfma_f32_32x32x16_bf16(a_, g_, accG, 0, 0, 0);
            accU = __builtin_amdgcn_mfma_f32_32x32x16_bf16(a_, u_, accU, 0, 0, 0);
            __builtin_amdgcn_s_setprio(0);
        }
    };

    const int nIter = HID / 32;   // 32
    stage(0, 0);
    stage(1, 32);
    PIPE_BARRIER(2)               // stage0 landed; stage1 (2 loads) in flight
    for (int i = 0; i < nIter; ++i) {
        int ks = (i + 2 < nIter) ? (i + 2) * 32 : 0;   // clamped dead stage keeps counts uniform
        stage((i + 2) % 3, ks);
        compute(i % 3);
        PIPE_BARRIER(2)           // stage(i+1) landed; newest stage in flight
    }

    // epilogue: silu(G)*U -> bf16 inter (D: col = lane&31, row = (r&3)+8*(r>>2)+4*kg)
    const int base_row = rowbase + wr * 32;
    const int col = i0 + wc * 32 + l31;
    #pragma unroll
    for (int r = 0; r < 16; ++r) {
        float g = accG[r];
        float u = accU[r];
        float v = g / (1.0f + __expf(-g)) * u;
        int row = base_row + (r & 3) + 8 * (r >> 2) + 4 * kg;
        inter[(size_t)row * ISZ + col] = (__bf16)v;
    }
}

// ---------------- FFN2: y[row] = bf16(rwt[row] * (inter[row] @ WdT')) ----------------
// BM=64, BN=128, BK=32, 3-buf depth-2 counted-vmcnt (vmcnt(3)). 36 KB -> 4 blocks/CU.
__global__ __launch_bounds__(256) void ffn2_kernel(
    const __bf16* __restrict__ inter, const __bf16* __restrict__ wdT,
    const float* __restrict__ rwt, const int* __restrict__ tiles64,
    __bf16* __restrict__ y)
{
    // grid 640 = 8 stripes x 80 tiles; XCD chunks of 80
    const int n  = blockIdx.x;
    const int nn = (n & 7) * 80 + (n >> 3);
    const int n0 = (nn / T64_MAX) * 128;       // stripe 0..7
    const int tv = tiles64[nn % T64_MAX];
    if (tv < 0) return;
    const int e = tv >> 16;
    const int rowbase = tv & 0xFFFF;

    __shared__ __align__(16) __bf16 sA[3][64][32];   // 12 KB
    __shared__ __align__(16) __bf16 sB[3][128][32];  // 24 KB -> 36 KB

    const int lane = threadIdx.x & 63;
    const int wid  = threadIdx.x >> 6;
    const int wr = wid >> 1, wc = wid & 1;
    const int l31 = lane & 31;
    const int kg  = lane >> 5;

    const int r16 = lane >> 2;
    const int cz  = (((lane & 3) ^ ((r16 >> 1) & 3)) * 8);
    const __bf16* A0 = inter + (size_t)(rowbase + wid * 16 + r16) * ISZ + cz;
    const __bf16* B0 = wdT + (size_t)e * HID * ISZ + (size_t)(n0 + wid * 32 + r16) * ISZ + cz;
    const size_t rstepB = (size_t)16 * ISZ;

    f32x16 acc[2];
    #pragma unroll
    for (int q = 0; q < 2; ++q)
        #pragma unroll
        for (int r = 0; r < 16; ++r) acc[q][r] = 0.f;

    auto stage = [&](int b, int k0) {   // 3 gload16 per wave
        gload16(A0 + k0,          &sA[b][wid * 16][0]);
        gload16(B0 + k0,          &sB[b][wid * 32][0]);
        gload16(B0 + k0 + rstepB, &sB[b][wid * 32 + 16][0]);
    };
    auto compute = [&](int b) {
        #pragma unroll
        for (int s = 0; s < 2; ++s) {
            const int ch = ((2 * s + kg) ^ ((l31 >> 1) & 3)) * 8;
            bf16x8 a_ = *(const bf16x8*)&sA[b][wr * 32 + l31][ch];
            bf16x8 b0 = *(const bf16x8*)&sB[b][wc * 64 + l31][ch];
            bf16x8 b1 = *(const bf16x8*)&sB[b][wc * 64 + 32 + l31][ch];
            __builtin_amdgcn_s_setprio(1);
            acc[0] = __builtin_amdgcn_mfma_f32_32x32x16_bf16(a_, b0, acc[0], 0, 0, 0);
            acc[1] = __builtin_amdgcn_mfma_f32_32x32x16_bf16(a_, b1, acc[1], 0, 0, 0);
            __builtin_amdgcn_s_setprio(0);
        }
    };

    const int nIter = ISZ / 32;   // 44
    stage(0, 0);
    stage(1, 32);
    PIPE_BARRIER(3)
    for (int i = 0; i < nIter; ++i) {
        int ks = (i + 2 < nIter) ? (i + 2) * 32 : 0;
        stage((i + 2) % 3, ks);
        compute(i % 3);
        PIPE_BARRIER(3)
    }

    const int base_row = rowbase + wr * 32;
    #pragma unroll
    for (int q = 0; q < 2; ++q) {
        const int col = n0 + wc * 64 + q * 32 + l31;
        #pragma unroll
        for (int r = 0; r < 16; ++r) {
            int row = base_row + (r & 3) + 8 * (r >> 2) + 4 * kg;
            y[(size_t)row * HID + col] = (__bf16)(rwt[row] * acc[q][r]);
        }
    }
}

// ---------------- Combine: out[t] = y[row0(t)] + y[row1(t)]  (y is bf16) ----------------
__global__ __launch_bounds__(256) void combine_kernel(
    const __bf16* __restrict__ y, const int* __restrict__ tok2row, float* __restrict__ out)
{
    const int idx = blockIdx.x * 256 + threadIdx.x;   // over T_TOKENS * HID/8
    const int t = idx >> 7;
    const int c = (idx & 127) * 8;
    const int r0 = tok2row[t * 2];
    const int r1 = tok2row[t * 2 + 1];
    bf16x8 a = *(const bf16x8*)(y + (size_t)r0 * HID + c);
    bf16x8 b = *(const bf16x8*)(y + (size_t)r1 * HID + c);
    float4 o0, o1;
    o0.x = (float)a[0] + (float)b[0]; o0.y = (float)a[1] + (float)b[1];
    o0.z = (float)a[2] + (float)b[2]; o0.w = (float)a[3] + (float)b[3];
    o1.x = (float)a[4] + (float)b[4]; o1.y = (float)a[5] + (float)b[5];
    o1.z = (float)a[6] + (float)b[6]; o1.w = (float)a[7] + (float)b[7];
    *(float4*)(out + (size_t)t * HID + c) = o0;
    *(float4*)(out + (size_t)t * HID + c + 4) = o1;
}

extern "C" void kernel_launch(void* const* d_in, const int* in_sizes, int n_in,
                              void* d_out, int out_size, void* d_ws, size_t ws_size,
                              hipStream_t stream) {
    const float* x  = (const float*)d_in[0];
    const float* gw = (const float*)d_in[1];
    const float* wg = (const float*)d_in[2];
    const float* wu = (const float*)d_in[3];
    const float* wd = (const float*)d_in[4];
    float* out = (float*)d_out;

    char* ws = (char*)d_ws;
    int*    tiles128 = (int*)(ws + 64);           // 40 ints
    int*    tiles64  = (int*)(ws + 384);          // 80 ints
    int*    sel      = (int*)(ws + 1024);         // 4096 ints -> 17408
    float*  wtp      = (float*)(ws + 17408);      // 4096 f32  -> 33792
    int*    rtok     = (int*)(ws + 33792);        // 5120 ints -> 54272
    float*  rwt      = (float*)(ws + 54272);      // 5120 f32  -> 74752
    int*    tok2row  = (int*)(ws + 74752);        // 4096 ints -> 91136
    __bf16* xb       = (__bf16*)(ws + 91136);     // 2049*1024 bf16 -> 4287488
    __bf16* inter    = (__bf16*)(ws + 4287488);   // 5120*1408 bf16 -> 18705408
    __bf16* wgT      = (__bf16*)(ws + 18705408);  // 23.07 MB -> 41774080
    __bf16* wuT      = (__bf16*)(ws + 41774080);  // 23.07 MB -> 64842752
    __bf16* wdT      = (__bf16*)(ws + 64842752);  // 23.07 MB -> 87911424
    __bf16* y        = (__bf16*)wgT;              // alias: wgT dead after ffn1 (10.5 MB)

    prep_kernel<<<4032, 256, 0, stream>>>(x, gw, sel, wtp, xb, wg, wu, wd, wgT, wuT, wdT);
    scan_assign_kernel<<<1, 1024, 0, stream>>>(tiles128, tiles64, sel, wtp, rtok, rwt, tok2row);

    // ffn1 (880, 8-wave) + deferred wd-cvt rider e4-7 (704)
    ffn1_kernel<<<22 * T128_MAX + 704, 512, 0, stream>>>(
        xb, rtok, wgT, wuT, tiles128, inter, wd, wdT);
    ffn2_kernel<<<8 * T64_MAX, 256, 0, stream>>>(inter, wdT, rwt, tiles64, y);          // 640
    combine_kernel<<<(T_TOKENS * HID / 8) / 256, 256, 0, stream>>>(y, tok2row, out);
}